// Round 10
// baseline (111.942 us; speedup 1.0000x reference)
//
#include <hip/hip_runtime.h>
#include <stdint.h>

// Problem constants
#define B_   2
#define S_   2048
#define HID  1024
#define NH   16
#define CH   64
#define MTOT (B_ * S_)          // 4096 rows
#define NELEM ((size_t)MTOT * HID)   // 4,194,304 per matrix
#define WELEM ((size_t)HID * HID)    // 1,048,576 per weight

typedef unsigned short u16;
typedef unsigned int u32;
typedef __attribute__((ext_vector_type(4))) float f32x4;
typedef __attribute__((ext_vector_type(8))) short s16x8;
typedef __attribute__((ext_vector_type(4))) short s16x4;

// ---------- helpers ----------
__device__ __forceinline__ u16 f2bf(float f) {
  union { float f; unsigned u; } v; v.f = f;
  unsigned u = v.u;
  return (u16)((u + 0x7FFFu + ((u >> 16) & 1u)) >> 16);  // RNE (R3/R4-verified)
}

__device__ __forceinline__ f32x4 mfma16(s16x8 a, s16x8 b, f32x4 c) {
  // v_mfma_f32_16x16x32_bf16: A row = lane&15, k = (lane>>4)*8+j (contig 16B);
  // B col = lane&15, same k; D col = lane&15, row = (lane>>4)*4+reg (m89-verified).
  asm("v_mfma_f32_16x16x32_bf16 %0, %1, %2, %0" : "+v"(c) : "v"(a), "v"(b));
  return c;
}

// Hazard-hardened variants (R7-PROVEN fix): s_nop 1 guards VALU-write ->
// MFMA-read (2-cycle rule); "+&v" early-clobber forbids A/B aliasing D.
__device__ __forceinline__ f32x4 mfma16h(s16x8 a, s16x8 b, f32x4 c) {
  asm("s_nop 1\n\tv_mfma_f32_16x16x32_bf16 %0, %1, %2, %0"
      : "+&v"(c) : "v"(a), "v"(b));
  return c;
}

// 16x16x16 bf16 MFMA (A/B: 2 VGPRs = 4 bf16, k = (lane>>4)*4 + elem).
__device__ __forceinline__ f32x4 mfma16k16h(s16x4 a, s16x4 b, f32x4 c) {
  asm("s_nop 1\n\tv_mfma_f32_16x16x16_bf16 %0, %1, %2, %0"
      : "+&v"(c) : "v"(a), "v"(b));
  return c;
}

__device__ __forceinline__ u32 cvtpk(float lo, float hi) {
  u32 r;
  asm("v_cvt_pk_bf16_f32 %0, %1, %2" : "=v"(r) : "v"(lo), "v"(hi));
  return r;
}

__device__ __forceinline__ void mfma_fence() {
  asm volatile("s_nop 7\n\ts_nop 7" ::: );
}

__device__ __forceinline__ void gload_lds16(const u16* g, u16* l) {
  __builtin_amdgcn_global_load_lds((const __attribute__((address_space(1))) void*)g,
                                   (__attribute__((address_space(3))) void*)l,
                                   16, 0, 0);
}

// ---------- kernel 1: fp32 -> bf16 convert of q,k,v ----------
__global__ __launch_bounds__(256) void k_convert(const float* __restrict__ a,
                                                 const float* __restrict__ b,
                                                 const float* __restrict__ c,
                                                 u16* __restrict__ out) {
  const float* src = (blockIdx.y == 0) ? a : (blockIdx.y == 1) ? b : c;
  u16* dst = out + (size_t)blockIdx.y * NELEM;
  size_t i = ((size_t)blockIdx.x * 256 + threadIdx.x) * 8;
  f32x4 v0 = *(const f32x4*)(src + i);
  f32x4 v1 = *(const f32x4*)(src + i + 4);
  s16x8 r;
#pragma unroll
  for (int k = 0; k < 4; ++k) { r[k] = (short)f2bf(v0[k]); r[4 + k] = (short)f2bf(v1[k]); }
  *(s16x8*)(dst + i) = r;
}

// ---------- kernel 2: W (fp32 [K][N]) -> W^T (bf16 [N][K]) ----------
__global__ __launch_bounds__(256) void k_transposeW(const float* __restrict__ w0,
                                                    const float* __restrict__ w1,
                                                    const float* __restrict__ w2,
                                                    u16* __restrict__ wT) {
  const float* w = (blockIdx.z == 0) ? w0 : (blockIdx.z == 1) ? w1 : w2;
  u16* o = wT + (size_t)blockIdx.z * WELEM;
  __shared__ u16 tile[64][65];
  int x = threadIdx.x & 63, y = threadIdx.x >> 6;
  int r0 = blockIdx.x * 64, c0 = blockIdx.y * 64;
#pragma unroll
  for (int i = 0; i < 16; ++i) {
    int r = i * 4 + y;
    tile[r][x] = f2bf(w[(size_t)(r0 + r) * HID + c0 + x]);
  }
  __syncthreads();
#pragma unroll
  for (int i = 0; i < 16; ++i) {
    int cc = i * 4 + y;
    o[(size_t)(c0 + cc) * HID + r0 + x] = tile[x][cc];
  }
}

// ---------- kernel 3: bf16 GEMM  C[M,N] = A[M,K] @ (BT[N,K])^T ----------
// m97 structure. z==0 (emb_q) scaled by 1/8. z==2 (emb_v) is written in
// PACKED V-FRAG layout for the attention PV mfma_16x16x16 B-operand:
// vfrag[bh][t/16][chblk(4)][hi(4)][ch16(16)][4 bf16 of t%16 = hi*4+0..3].
__global__ __launch_bounds__(256) void k_gemm(const u16* __restrict__ Aall,
                                              const u16* __restrict__ BTall,
                                              u16* __restrict__ Call,
                                              u16* __restrict__ Vfrag) {
  const u16* A  = Aall  + (size_t)blockIdx.z * NELEM;
  const u16* BT = BTall + (size_t)blockIdx.z * WELEM;
  u16*       C  = Call  + (size_t)blockIdx.z * NELEM;
  int row0 = blockIdx.y * 128, col0 = blockIdx.x * 128;

  __shared__ __align__(16) u16 sA[128 * 32];
  __shared__ __align__(16) u16 sB[128 * 32];

  int t = threadIdx.x;
  int wave = t >> 6, lane = t & 63;
  int lrow = lane & 15, lhi = lane >> 4;
  int wr = wave >> 1, wc = wave & 1;

  f32x4 acc[4][4] = {};

  for (int kt = 0; kt < HID; kt += 32) {
#pragma unroll
    for (int r = 0; r < 2; ++r) {
      int idx = r * 256 + t;
      int srow = idx >> 2, scol = (idx & 3) << 3;
      int ldsoff = (r * 256 + wave * 64) * 8;   // wave-uniform LDS base
      gload_lds16(A  + (size_t)(row0 + srow) * HID + kt + scol, sA + ldsoff);
      gload_lds16(BT + (size_t)(col0 + srow) * HID + kt + scol, sB + ldsoff);
    }
    __syncthreads();
    s16x8 af[4], bfr[4];
#pragma unroll
    for (int m = 0; m < 4; ++m)
      af[m] = *(const s16x8*)&sA[(wr * 64 + m * 16 + lrow) * 32 + lhi * 8];
#pragma unroll
    for (int n = 0; n < 4; ++n)
      bfr[n] = *(const s16x8*)&sB[(wc * 64 + n * 16 + lrow) * 32 + lhi * 8];
#pragma unroll
    for (int m = 0; m < 4; ++m)
#pragma unroll
      for (int n = 0; n < 4; ++n)
        acc[m][n] = mfma16(af[m], bfr[n], acc[m][n]);
    __syncthreads();
  }
  mfma_fence();
  if (blockIdx.z == 2) {
    // packed V-frag epilogue (R9-verified)
#pragma unroll
    for (int m = 0; m < 4; ++m)
#pragma unroll
      for (int n = 0; n < 4; ++n) {
        int rr = row0 + wr * 64 + m * 16 + lhi * 4;       // t-row of j=0
        int cc = col0 + wc * 64 + n * 16 + lrow;          // hidden col
        int bb = rr >> 11, tt = rr & 2047;
        int hh = cc >> 6, chl = cc & 63;
        size_t off = ((size_t)(bb * NH + hh)) * ((size_t)CH * S_) +
                     (size_t)(((tt >> 4) * 4 + (chl >> 4)) * 256 +
                              ((tt >> 2) & 3) * 64 + (chl & 15) * 4);
        u32 w0 = (u32)f2bf(acc[m][n][0]) | ((u32)f2bf(acc[m][n][1]) << 16);
        u32 w1 = (u32)f2bf(acc[m][n][2]) | ((u32)f2bf(acc[m][n][3]) << 16);
        uint2 w; w.x = w0; w.y = w1;
        *(uint2*)&Vfrag[off] = w;
      }
  } else {
    float scl = (blockIdx.z == 0) ? 0.125f : 1.0f;   // fold 1/sqrt(64) into emb_q
#pragma unroll
    for (int m = 0; m < 4; ++m)
#pragma unroll
      for (int n = 0; n < 4; ++n)
#pragma unroll
        for (int j = 0; j < 4; ++j) {
          int rr = row0 + wr * 64 + m * 16 + lhi * 4 + j;
          int cc = col0 + wc * 64 + n * 16 + lrow;
          C[(size_t)rr * HID + cc] = f2bf(acc[m][n][j] * scl);
        }
  }
}

// ---------- kernel 4: causal flash attention ----------
// R10: 4 waves x 32 q-rows (QTILE=128) — halves per-CU LDS-pipe traffic vs
// R9's 8x16 (K/V frags amortized over 2 q-sub-tiles per wave; LDS was 83%
// of step time). Swapped QK^T -> in-register P (cvt_pk), packed V-frags,
// fixed-max softmax, deferred row-sum: all R9-verified, now with mi in {0,1}.
__global__ __launch_bounds__(256) void k_attn(const u16* __restrict__ eq,
                                              const u16* __restrict__ ek,
                                              const u16* __restrict__ vf,
                                              float* __restrict__ out) {
  int bh = blockIdx.y;                 // b*NH + h
  int b = bh >> 4, h = bh & 15;
  // causal load balance: pair q-tile k with 15-k across the two bh halves
  int qt = (blockIdx.y & 16) ? (int)blockIdx.x : (15 - (int)blockIdx.x);
  int q0b = qt * 128;
  int wave = threadIdx.x >> 6, lane = threadIdx.x & 63;
  int lrow = lane & 15, lhi = lane >> 4;
  int q0w0 = q0b + wave * 32;          // wave owns q0w0 .. q0w0+31 (mi=0,1)

  __shared__ __align__(16) u16 sK[2][64 * 64];
  __shared__ __align__(16) u16 sV[2][4096];

  const u16* gK = ek + (size_t)(b * S_) * HID + h * CH;
  const u16* gV = vf + (size_t)bh * ((size_t)CH * S_);

  // Q fragments (emb_q pre-scaled by 1/8); swapped-QK B-frag layout.
  s16x8 qf[2][2];
#pragma unroll
  for (int mi = 0; mi < 2; ++mi) {
    size_t qbase = (size_t)(b * S_ + q0w0 + mi * 16 + lrow) * HID + h * CH;
    qf[mi][0] = *(const s16x8*)(eq + qbase + lhi * 8);
    qf[mi][1] = *(const s16x8*)(eq + qbase + 32 + lhi * 8);
  }

  f32x4 o[2][4] = {};            // o[mi][chblk]: D col=ch16=lrow, row=q=lhi*4+reg
  float lsum[2] = {0.f, 0.f};    // per-lane partial row-sum for q = lrow (per mi)

  // K staging lane mapping (XOR-swizzled; chunk = 8 t-rows; wave stages 2w,2w+1)
  int lr8 = lane >> 3, slot = lane & 7;
  int co = ((slot ^ lr8) << 3);  // inverse-swizzled source column (elems)

  // prologue: stage tile 0
#pragma unroll
  for (int i = 0; i < 2; ++i) {
    int c = wave * 2 + i;
    gload_lds16(gK + (size_t)(c * 8 + lr8) * HID + co, &sK[0][c * 512]);
    gload_lds16(gV + (size_t)c * 512 + lane * 8, &sV[0][c * 512]);
  }

  int nsteps = q0b / 64 + 2;
  for (int st = 0; st < nsteps; ++st) {
    int tb = st * 64;
    __syncthreads();                       // stage(st) complete in all waves
    if (st + 1 < nsteps) {                 // prefetch next tile into other buf
      int tb2 = tb + 64;
      int bufn = (st + 1) & 1;
#pragma unroll
      for (int i = 0; i < 2; ++i) {
        int c = wave * 2 + i;
        gload_lds16(gK + (size_t)(tb2 + c * 8 + lr8) * HID + co, &sK[bufn][c * 512]);
        gload_lds16(gV + (size_t)(tb2 >> 4) * 1024 + c * 512 + lane * 8,
                    &sV[bufn][c * 512]);
      }
    }
    if (tb > q0w0 + 31) continue;          // fully masked for this wave

    const u16* kb = sK[st & 1];
    const u16* vb = sV[st & 1];

    // ---- QK^T swapped: 16 MFMA; p[mi][kvf][j] = S[t][q], K-frags shared ----
    f32x4 p[2][4];
#pragma unroll
    for (int kvf = 0; kvf < 4; ++kvf) {
      int row = kvf * 16 + lrow;
      int sw = row & 7;
      s16x8 k0 = *(const s16x8*)(kb + row * 64 + ((lhi ^ sw) << 3));
      s16x8 k1 = *(const s16x8*)(kb + row * 64 + (((4 + lhi) ^ sw) << 3));
#pragma unroll
      for (int mi = 0; mi < 2; ++mi) {
        f32x4 acc = {0.f, 0.f, 0.f, 0.f};
        acc = mfma16h(k0, qf[mi][0], acc);
        acc = mfma16h(k1, qf[mi][1], acc);
        p[mi][kvf] = acc;
      }
    }
    mfma_fence();

    // ---- softmax numerators (fixed max = 0) -> in-register PV A-frags ----
    s16x4 pa[2][4];
#pragma unroll
    for (int mi = 0; mi < 2; ++mi) {
      int q0w = q0w0 + mi * 16;
      bool need_mask = (tb + 63 > q0w);
#pragma unroll
      for (int kvf = 0; kvf < 4; ++kvf) {
        float e[4];
#pragma unroll
        for (int j = 0; j < 4; ++j) {
          float v = p[mi][kvf][j];
          if (need_mask && (tb + kvf * 16 + lhi * 4 + j > q0w + lrow)) v = -3.0e38f;
          e[j] = __expf(v);
        }
        lsum[mi] += (e[0] + e[1]) + (e[2] + e[3]);
        union { u32 u[2]; s16x4 v4; } pk;
        pk.u[0] = cvtpk(e[0], e[1]);
        pk.u[1] = cvtpk(e[2], e[3]);
        pa[mi][kvf] = pk.v4;
      }
    }

    // ---- PV: 32 x mfma_16x16x16; V-frags read once, shared across mi ----
#pragma unroll
    for (int n = 0; n < 4; ++n)
#pragma unroll
      for (int kvf = 0; kvf < 4; ++kvf) {
        s16x4 vfr = *(const s16x4*)&vb[(kvf * 4 + n) * 256 + lhi * 64 + lrow * 4];
        o[0][n] = mfma16k16h(pa[0][kvf], vfr, o[0][n]);
        o[1][n] = mfma16k16h(pa[1][kvf], vfr, o[1][n]);
      }
  }
  mfma_fence();

  // reduce lsum across the 4 hi-groups: lanes end with totals for q = lrow
#pragma unroll
  for (int mi = 0; mi < 2; ++mi) {
    lsum[mi] += __shfl_xor(lsum[mi], 16);
    lsum[mi] += __shfl_xor(lsum[mi], 32);
  }

#pragma unroll
  for (int mi = 0; mi < 2; ++mi)
#pragma unroll
    for (int j = 0; j < 4; ++j) {
      float ls = __shfl(lsum[mi], lhi * 4 + j);   // total for q-row lhi*4+j
      float inv = 1.0f / ls;
      int q = q0w0 + mi * 16 + lhi * 4 + j;
      float* op = out + (size_t)(b * S_ + q) * HID + h * CH + lrow;
#pragma unroll
      for (int n = 0; n < 4; ++n)
        op[n * 16] = o[mi][n][j] * inv;
    }
}

// ---------- launch ----------
extern "C" void kernel_launch(void* const* d_in, const int* in_sizes, int n_in,
                              void* d_out, int out_size, void* d_ws, size_t ws_size,
                              hipStream_t stream) {
  const float* q  = (const float*)d_in[0];
  const float* k  = (const float*)d_in[1];
  const float* v  = (const float*)d_in[2];
  const float* wq = (const float*)d_in[3];
  const float* wk = (const float*)d_in[4];
  const float* wv = (const float*)d_in[5];
  float* out = (float*)d_out;

  u16* qkv = (u16*)d_ws;                 // 3 * NELEM
  u16* wT  = qkv + 3 * NELEM;            // 3 * WELEM
  u16* emb = wT + 3 * WELEM;             // 3 * NELEM (z=2 slot unused for C)
  u16* vfr = emb + 2 * NELEM;            // packed V-frag written by k_gemm z==2

  k_convert<<<dim3(2048, 3), 256, 0, stream>>>(q, k, v, qkv);
  k_transposeW<<<dim3(16, 16, 3), 256, 0, stream>>>(wq, wk, wv, wT);
  k_gemm<<<dim3(HID / 128, MTOT / 128, 3), 256, 0, stream>>>(qkv, wT, emb, vfr);
  k_attn<<<dim3(S_ / 128, B_ * NH), 256, 0, stream>>>(emb, emb + NELEM, vfr, out);
}

// Round 11
// 103.290 us; speedup vs baseline: 1.0838x; 1.0838x over previous
//
#include <hip/hip_runtime.h>
#include <stdint.h>

// Problem constants
#define B_   2
#define S_   2048
#define HID  1024
#define NH   16
#define CH   64
#define MTOT (B_ * S_)          // 4096 rows
#define NELEM ((size_t)MTOT * HID)   // 4,194,304 per matrix
#define WELEM ((size_t)HID * HID)    // 1,048,576 per weight

typedef unsigned short u16;
typedef unsigned int u32;
typedef __attribute__((ext_vector_type(4))) float f32x4;
typedef __attribute__((ext_vector_type(8))) short s16x8;
typedef __attribute__((ext_vector_type(4))) short s16x4;

// ---------- helpers ----------
__device__ __forceinline__ u16 f2bf(float f) {
  union { float f; unsigned u; } v; v.f = f;
  unsigned u = v.u;
  return (u16)((u + 0x7FFFu + ((u >> 16) & 1u)) >> 16);  // RNE (R3/R4-verified)
}

__device__ __forceinline__ f32x4 mfma16(s16x8 a, s16x8 b, f32x4 c) {
  // v_mfma_f32_16x16x32_bf16: A row = lane&15, k = (lane>>4)*8+j (contig 16B);
  // B col = lane&15, same k; D col = lane&15, row = (lane>>4)*4+reg (m89-verified).
  asm("v_mfma_f32_16x16x32_bf16 %0, %1, %2, %0" : "+v"(c) : "v"(a), "v"(b));
  return c;
}

// Hazard-hardened variants (R7-PROVEN fix): s_nop 1 guards VALU-write ->
// MFMA-read (2-cycle rule); "+&v" early-clobber forbids A/B aliasing D.
__device__ __forceinline__ f32x4 mfma16h(s16x8 a, s16x8 b, f32x4 c) {
  asm("s_nop 1\n\tv_mfma_f32_16x16x32_bf16 %0, %1, %2, %0"
      : "+&v"(c) : "v"(a), "v"(b));
  return c;
}

// 16x16x16 bf16 MFMA (A/B: 2 VGPRs = 4 bf16, k = (lane>>4)*4 + elem).
__device__ __forceinline__ f32x4 mfma16k16h(s16x4 a, s16x4 b, f32x4 c) {
  asm("s_nop 1\n\tv_mfma_f32_16x16x16_bf16 %0, %1, %2, %0"
      : "+&v"(c) : "v"(a), "v"(b));
  return c;
}

__device__ __forceinline__ u32 cvtpk(float lo, float hi) {
  u32 r;
  asm("v_cvt_pk_bf16_f32 %0, %1, %2" : "=v"(r) : "v"(lo), "v"(hi));
  return r;
}

__device__ __forceinline__ void mfma_fence() {
  asm volatile("s_nop 7\n\ts_nop 7" ::: );
}

__device__ __forceinline__ void gload_lds16(const u16* g, u16* l) {
  __builtin_amdgcn_global_load_lds((const __attribute__((address_space(1))) void*)g,
                                   (__attribute__((address_space(3))) void*)l,
                                   16, 0, 0);
}

// ---------- kernel 1: fp32 -> bf16 convert of q,k,v ----------
__global__ __launch_bounds__(256) void k_convert(const float* __restrict__ a,
                                                 const float* __restrict__ b,
                                                 const float* __restrict__ c,
                                                 u16* __restrict__ out) {
  const float* src = (blockIdx.y == 0) ? a : (blockIdx.y == 1) ? b : c;
  u16* dst = out + (size_t)blockIdx.y * NELEM;
  size_t i = ((size_t)blockIdx.x * 256 + threadIdx.x) * 8;
  f32x4 v0 = *(const f32x4*)(src + i);
  f32x4 v1 = *(const f32x4*)(src + i + 4);
  s16x8 r;
#pragma unroll
  for (int k = 0; k < 4; ++k) { r[k] = (short)f2bf(v0[k]); r[4 + k] = (short)f2bf(v1[k]); }
  *(s16x8*)(dst + i) = r;
}

// ---------- kernel 2: W (fp32 [K][N]) -> W^T (bf16 [N][K]) ----------
__global__ __launch_bounds__(256) void k_transposeW(const float* __restrict__ w0,
                                                    const float* __restrict__ w1,
                                                    const float* __restrict__ w2,
                                                    u16* __restrict__ wT) {
  const float* w = (blockIdx.z == 0) ? w0 : (blockIdx.z == 1) ? w1 : w2;
  u16* o = wT + (size_t)blockIdx.z * WELEM;
  __shared__ u16 tile[64][65];
  int x = threadIdx.x & 63, y = threadIdx.x >> 6;
  int r0 = blockIdx.x * 64, c0 = blockIdx.y * 64;
#pragma unroll
  for (int i = 0; i < 16; ++i) {
    int r = i * 4 + y;
    tile[r][x] = f2bf(w[(size_t)(r0 + r) * HID + c0 + x]);
  }
  __syncthreads();
#pragma unroll
  for (int i = 0; i < 16; ++i) {
    int cc = i * 4 + y;
    o[(size_t)(c0 + cc) * HID + r0 + x] = tile[x][cc];
  }
}

// ---------- kernel 3: bf16 GEMM  C[M,N] = A[M,K] @ (BT[N,K])^T ----------
// m97 structure. z==0 (emb_q) scaled by (1/8)*ln2inv so attention can use
// exp2 directly. z==2 (emb_v) written in PACKED V-FRAG layout (R9-verified).
__global__ __launch_bounds__(256) void k_gemm(const u16* __restrict__ Aall,
                                              const u16* __restrict__ BTall,
                                              u16* __restrict__ Call,
                                              u16* __restrict__ Vfrag) {
  const u16* A  = Aall  + (size_t)blockIdx.z * NELEM;
  const u16* BT = BTall + (size_t)blockIdx.z * WELEM;
  u16*       C  = Call  + (size_t)blockIdx.z * NELEM;
  int row0 = blockIdx.y * 128, col0 = blockIdx.x * 128;

  __shared__ __align__(16) u16 sA[128 * 32];
  __shared__ __align__(16) u16 sB[128 * 32];

  int t = threadIdx.x;
  int wave = t >> 6, lane = t & 63;
  int lrow = lane & 15, lhi = lane >> 4;
  int wr = wave >> 1, wc = wave & 1;

  f32x4 acc[4][4] = {};

  for (int kt = 0; kt < HID; kt += 32) {
#pragma unroll
    for (int r = 0; r < 2; ++r) {
      int idx = r * 256 + t;
      int srow = idx >> 2, scol = (idx & 3) << 3;
      int ldsoff = (r * 256 + wave * 64) * 8;   // wave-uniform LDS base
      gload_lds16(A  + (size_t)(row0 + srow) * HID + kt + scol, sA + ldsoff);
      gload_lds16(BT + (size_t)(col0 + srow) * HID + kt + scol, sB + ldsoff);
    }
    __syncthreads();
    s16x8 af[4], bfr[4];
#pragma unroll
    for (int m = 0; m < 4; ++m)
      af[m] = *(const s16x8*)&sA[(wr * 64 + m * 16 + lrow) * 32 + lhi * 8];
#pragma unroll
    for (int n = 0; n < 4; ++n)
      bfr[n] = *(const s16x8*)&sB[(wc * 64 + n * 16 + lrow) * 32 + lhi * 8];
#pragma unroll
    for (int m = 0; m < 4; ++m)
#pragma unroll
      for (int n = 0; n < 4; ++n)
        acc[m][n] = mfma16(af[m], bfr[n], acc[m][n]);
    __syncthreads();
  }
  mfma_fence();
  if (blockIdx.z == 2) {
    // packed V-frag epilogue (R9-verified)
#pragma unroll
    for (int m = 0; m < 4; ++m)
#pragma unroll
      for (int n = 0; n < 4; ++n) {
        int rr = row0 + wr * 64 + m * 16 + lhi * 4;       // t-row of j=0
        int cc = col0 + wc * 64 + n * 16 + lrow;          // hidden col
        int bb = rr >> 11, tt = rr & 2047;
        int hh = cc >> 6, chl = cc & 63;
        size_t off = ((size_t)(bb * NH + hh)) * ((size_t)CH * S_) +
                     (size_t)(((tt >> 4) * 4 + (chl >> 4)) * 256 +
                              ((tt >> 2) & 3) * 64 + (chl & 15) * 4);
        u32 w0 = (u32)f2bf(acc[m][n][0]) | ((u32)f2bf(acc[m][n][1]) << 16);
        u32 w1 = (u32)f2bf(acc[m][n][2]) | ((u32)f2bf(acc[m][n][3]) << 16);
        uint2 w; w.x = w0; w.y = w1;
        *(uint2*)&Vfrag[off] = w;
      }
  } else {
    // z==0: fold 1/sqrt(64) AND 1/ln(2) so k_attn uses exp2f directly
    float scl = (blockIdx.z == 0) ? 0.125f * 1.44269504f : 1.0f;
#pragma unroll
    for (int m = 0; m < 4; ++m)
#pragma unroll
      for (int n = 0; n < 4; ++n)
#pragma unroll
        for (int j = 0; j < 4; ++j) {
          int rr = row0 + wr * 64 + m * 16 + lhi * 4 + j;
          int cc = col0 + wc * 64 + n * 16 + lrow;
          C[(size_t)rr * HID + cc] = f2bf(acc[m][n][j] * scl);
        }
  }
}

// ---------- kernel 4: causal flash attention, KV-SPLIT partials ----------
// R9-proven inner structure (8 waves x 16 q-rows, KVBLK=64, swapped QK^T,
// in-register P via cvt_pk, packed V-frags, fixed-max softmax).
// NEW: each (bh, qt) splits its 2(qt+1) steps into two HALVES -> grid
// (32 bh, 32) = 1024 equal-per-qt blocks, heavy-first (y: qt descending);
// 4 blocks/CU x 8 waves = 32 waves/CU SUSTAINED. Partials are unnormalized
// (fixed max -> combine is pure addition): half 0 -> op0 (=d_out),
// half 1 -> op1; per-row lsum partial -> lp[half].
__global__ __launch_bounds__(512) void k_attn(const u16* __restrict__ eq,
                                              const u16* __restrict__ ek,
                                              const u16* __restrict__ vf,
                                              float* __restrict__ op0,
                                              float* __restrict__ op1,
                                              float* __restrict__ lp) {
  int bh = blockIdx.x;                 // b*NH + h
  int b = bh >> 4, h = bh & 15;
  int yy = blockIdx.y;                 // heavy-first: qt = 15 - (yy>>1)
  int qt = 15 - (yy >> 1);
  int half = yy & 1;
  int q0b = qt * 128;
  int wave = threadIdx.x >> 6, lane = threadIdx.x & 63;
  int lrow = lane & 15, lhi = lane >> 4;
  int q0w = q0b + wave * 16;

  __shared__ __align__(16) u16 sK[2][64 * 64];
  __shared__ __align__(16) u16 sV[2][4096];

  const u16* gK = ek + (size_t)(b * S_) * HID + h * CH;
  const u16* gV = vf + (size_t)bh * ((size_t)CH * S_);

  // Q fragments (emb_q pre-scaled); swapped-QK B-frag layout.
  s16x8 qf[2];
  {
    size_t qbase = (size_t)(b * S_ + q0w + lrow) * HID + h * CH;
    qf[0] = *(const s16x8*)(eq + qbase + lhi * 8);
    qf[1] = *(const s16x8*)(eq + qbase + 32 + lhi * 8);
  }

  f32x4 o[4] = {};                 // o[chblk]: D col=ch16=lrow, row=q=lhi*4+reg
  float lsum = 0.0f;               // per-lane partial row-sum for q = lrow

  // K staging lane mapping (XOR-swizzled; chunk = 8 t-rows; wave stages chunk w)
  int lr8 = lane >> 3, slot = lane & 7;
  int co = ((slot ^ lr8) << 3);    // inverse-swizzled source column (elems)

  int nst = qt + 1;                // steps in this half
  int sbase = half * nst;          // global step offset
  int tb0 = sbase * 64;

  // prologue: stage first tile of this half
  gload_lds16(gK + (size_t)(tb0 + wave * 8 + lr8) * HID + co, &sK[0][wave * 512]);
  gload_lds16(gV + (size_t)(tb0 >> 4) * 1024 + wave * 512 + lane * 8, &sV[0][wave * 512]);

  for (int st = 0; st < nst; ++st) {
    int tb = (sbase + st) * 64;
    __syncthreads();                       // stage(st) complete in all waves
    if (st + 1 < nst) {                    // prefetch next tile into other buf
      int tb2 = tb + 64;
      int bufn = (st + 1) & 1;
      gload_lds16(gK + (size_t)(tb2 + wave * 8 + lr8) * HID + co, &sK[bufn][wave * 512]);
      gload_lds16(gV + (size_t)(tb2 >> 4) * 1024 + wave * 512 + lane * 8,
                  &sV[bufn][wave * 512]);
    }
    if (tb > q0w + 15) continue;           // fully masked for this wave

    const u16* kb = sK[st & 1];
    const u16* vb = sV[st & 1];

    // ---- QK^T swapped: 8 MFMA; p[kvf][j] = S[t=tb+kvf*16+lhi*4+j][q=q0w+lrow]
    f32x4 p[4];
#pragma unroll
    for (int kvf = 0; kvf < 4; ++kvf) {
      int row = kvf * 16 + lrow;
      int sw = row & 7;
      s16x8 k0 = *(const s16x8*)(kb + row * 64 + ((lhi ^ sw) << 3));
      s16x8 k1 = *(const s16x8*)(kb + row * 64 + (((4 + lhi) ^ sw) << 3));
      f32x4 acc = {0.f, 0.f, 0.f, 0.f};
      acc = mfma16h(k0, qf[0], acc);
      acc = mfma16h(k1, qf[1], acc);
      p[kvf] = acc;
    }
    mfma_fence();

    // ---- softmax numerators (fixed max = 0, exp2 domain) ----
    bool need_mask = (tb + 63 > q0w);
    s16x4 pa[4];
#pragma unroll
    for (int kvf = 0; kvf < 4; ++kvf) {
      float e[4];
#pragma unroll
      for (int j = 0; j < 4; ++j) {
        float v = p[kvf][j];
        if (need_mask && (tb + kvf * 16 + lhi * 4 + j > q0w + lrow)) v = -3.0e38f;
        e[j] = exp2f(v);
      }
      lsum += (e[0] + e[1]) + (e[2] + e[3]);
      union { u32 u[2]; s16x4 v4; } pk;
      pk.u[0] = cvtpk(e[0], e[1]);
      pk.u[1] = cvtpk(e[2], e[3]);
      pa[kvf] = pk.v4;
    }

    // ---- PV: 16 x mfma_16x16x16, V read as linear b64 B-frags ----
#pragma unroll
    for (int n = 0; n < 4; ++n)
#pragma unroll
      for (int kvf = 0; kvf < 4; ++kvf) {
        s16x4 vfr = *(const s16x4*)&vb[(kvf * 4 + n) * 256 + lhi * 64 + lrow * 4];
        o[n] = mfma16k16h(pa[kvf], vfr, o[n]);
      }
  }
  mfma_fence();

  // reduce lsum across the 4 hi-groups: every lane ends with total for q = lrow
  lsum += __shfl_xor(lsum, 16);
  lsum += __shfl_xor(lsum, 32);

  float* ob = half ? op1 : op0;
#pragma unroll
  for (int j = 0; j < 4; ++j) {
    int q = q0w + lhi * 4 + j;
    float* op = ob + (size_t)(b * S_ + q) * HID + h * CH + lrow;
#pragma unroll
    for (int n = 0; n < 4; ++n)
      op[n * 16] = o[n][j];              // unnormalized partial
  }
  if (lhi == 0) {                        // one lane set per q-row
    int q = q0w + lrow;
    lp[(((size_t)half * B_ + b) * S_ + q) * NH + h] = lsum;
  }
}

// ---------- kernel 5: combine partials + normalize ----------
__global__ __launch_bounds__(256) void k_combine(float* __restrict__ out,
                                                 const float* __restrict__ p1,
                                                 const float* __restrict__ lp) {
  size_t i = ((size_t)blockIdx.x * 256 + threadIdx.x) * 4;
  size_t row = i >> 10;                  // b*S + s
  int h = (int)((i & 1023) >> 6);
  size_t b = row >> 11, s = row & 2047;
  float l0 = lp[((0 * B_ + b) * S_ + s) * NH + h];
  float l1 = lp[((1 * B_ + b) * S_ + s) * NH + h];
  float inv = 1.0f / (l0 + l1);
  f32x4 a = *(const f32x4*)(out + i);
  f32x4 c = *(const f32x4*)(p1 + i);
#pragma unroll
  for (int k = 0; k < 4; ++k) a[k] = (a[k] + c[k]) * inv;
  *(f32x4*)(out + i) = a;
}

// ---------- launch ----------
extern "C" void kernel_launch(void* const* d_in, const int* in_sizes, int n_in,
                              void* d_out, int out_size, void* d_ws, size_t ws_size,
                              hipStream_t stream) {
  const float* q  = (const float*)d_in[0];
  const float* k  = (const float*)d_in[1];
  const float* v  = (const float*)d_in[2];
  const float* wq = (const float*)d_in[3];
  const float* wk = (const float*)d_in[4];
  const float* wv = (const float*)d_in[5];
  float* out = (float*)d_out;

  u16* qkv = (u16*)d_ws;                 // 3 * NELEM (dead after k_gemm)
  u16* wT  = qkv + 3 * NELEM;            // 3 * WELEM (dead after k_gemm)
  u16* emb = wT + 3 * WELEM;             // 3 * NELEM (z2 slot holds V-frag)
  u16* vfr = emb + 2 * NELEM;            // packed V-frag written by k_gemm z==2

  // partial buffers reuse dead regions: op0 = d_out, op1 + lp in qkv region
  float* op1 = (float*)d_ws;             // NELEM fp32 = 16 MB (< qkv's 24 MB)
  float* lp  = op1 + NELEM;              // 2*B*S*NH fp32 = 512 KB

  k_convert<<<dim3(2048, 3), 256, 0, stream>>>(q, k, v, qkv);
  k_transposeW<<<dim3(16, 16, 3), 256, 0, stream>>>(wq, wk, wv, wT);
  k_gemm<<<dim3(HID / 128, MTOT / 128, 3), 256, 0, stream>>>(qkv, wT, emb, vfr);
  k_attn<<<dim3(B_ * NH, 32), 512, 0, stream>>>(emb, emb + NELEM, vfr,
                                                out, op1, lp);
  k_combine<<<dim3(NELEM / (256 * 4)), 256, 0, stream>>>(out, op1, lp);
}

// Round 13
// 102.037 us; speedup vs baseline: 1.0971x; 1.0123x over previous
//
#include <hip/hip_runtime.h>
#include <stdint.h>

// Problem constants
#define B_   2
#define S_   2048
#define HID  1024
#define NH   16
#define CH   64
#define MTOT (B_ * S_)          // 4096 rows
#define NELEM ((size_t)MTOT * HID)   // 4,194,304 per matrix
#define WELEM ((size_t)HID * HID)    // 1,048,576 per weight

typedef unsigned short u16;
typedef unsigned int u32;
typedef __attribute__((ext_vector_type(4))) float f32x4;
typedef __attribute__((ext_vector_type(8))) short s16x8;
typedef __attribute__((ext_vector_type(4))) short s16x4;

// ---------- helpers ----------
__device__ __forceinline__ u16 f2bf(float f) {
  union { float f; unsigned u; } v; v.f = f;
  unsigned u = v.u;
  return (u16)((u + 0x7FFFu + ((u >> 16) & 1u)) >> 16);  // RNE (R3/R4-verified)
}

__device__ __forceinline__ f32x4 mfma16(s16x8 a, s16x8 b, f32x4 c) {
  // v_mfma_f32_16x16x32_bf16 (m89-verified layouts). GEMM-only (11 rounds clean).
  asm("v_mfma_f32_16x16x32_bf16 %0, %1, %2, %0" : "+v"(c) : "v"(a), "v"(b));
  return c;
}

// D != C form: SrcC is a separate (persistent, never-rewritten) register --
// no per-chain v_mov copies, hence NO VALU->SrcC hazard, no s_nop needed.
// "=&v" early-clobber keeps D disjoint from A/B/C.
__device__ __forceinline__ f32x4 mfma16z(s16x8 a, s16x8 b, f32x4 c) {
  f32x4 d;
  asm("v_mfma_f32_16x16x32_bf16 %0, %1, %2, %3"
      : "=&v"(d) : "v"(a), "v"(b), "v"(c));
  return d;
}

// Tied same-register accumulate (HW-interlocked MFMA->MFMA same-acc chain).
// (R12 compile bug: this said 32x32x16 with 4-reg operands; fixed to 16x16x32.)
__device__ __forceinline__ f32x4 mfma16t(s16x8 a, s16x8 b, f32x4 c) {
  asm("v_mfma_f32_16x16x32_bf16 %0, %1, %2, %0" : "+&v"(c) : "v"(a), "v"(b));
  return c;
}

// 16x16x16 bf16, tied accumulate (o[n] regs only ever written by MFMA in-loop).
__device__ __forceinline__ f32x4 mfma16k16t(s16x4 a, s16x4 b, f32x4 c) {
  asm("v_mfma_f32_16x16x16_bf16 %0, %1, %2, %0" : "+&v"(c) : "v"(a), "v"(b));
  return c;
}

__device__ __forceinline__ u32 cvtpk(float lo, float hi) {
  u32 r;
  asm("v_cvt_pk_bf16_f32 %0, %1, %2" : "=v"(r) : "v"(lo), "v"(hi));
  return r;
}

// 24-cycle fence before VALU reads of MFMA D results.
__device__ __forceinline__ void mfma_fence() {
  asm volatile("s_nop 7\n\ts_nop 7\n\ts_nop 7" ::: );
}

__device__ __forceinline__ void gload_lds16(const u16* g, u16* l) {
  __builtin_amdgcn_global_load_lds((const __attribute__((address_space(1))) void*)g,
                                   (__attribute__((address_space(3))) void*)l,
                                   16, 0, 0);
}

// ---------- kernel 1: fp32 -> bf16 convert of q,k,v ----------
__global__ __launch_bounds__(256) void k_convert(const float* __restrict__ a,
                                                 const float* __restrict__ b,
                                                 const float* __restrict__ c,
                                                 u16* __restrict__ out) {
  const float* src = (blockIdx.y == 0) ? a : (blockIdx.y == 1) ? b : c;
  u16* dst = out + (size_t)blockIdx.y * NELEM;
  size_t i = ((size_t)blockIdx.x * 256 + threadIdx.x) * 8;
  f32x4 v0 = *(const f32x4*)(src + i);
  f32x4 v1 = *(const f32x4*)(src + i + 4);
  s16x8 r;
#pragma unroll
  for (int k = 0; k < 4; ++k) { r[k] = (short)f2bf(v0[k]); r[4 + k] = (short)f2bf(v1[k]); }
  *(s16x8*)(dst + i) = r;
}

// ---------- kernel 2: W (fp32 [K][N]) -> W^T (bf16 [N][K]) ----------
__global__ __launch_bounds__(256) void k_transposeW(const float* __restrict__ w0,
                                                    const float* __restrict__ w1,
                                                    const float* __restrict__ w2,
                                                    u16* __restrict__ wT) {
  const float* w = (blockIdx.z == 0) ? w0 : (blockIdx.z == 1) ? w1 : w2;
  u16* o = wT + (size_t)blockIdx.z * WELEM;
  __shared__ u16 tile[64][65];
  int x = threadIdx.x & 63, y = threadIdx.x >> 6;
  int r0 = blockIdx.x * 64, c0 = blockIdx.y * 64;
#pragma unroll
  for (int i = 0; i < 16; ++i) {
    int r = i * 4 + y;
    tile[r][x] = f2bf(w[(size_t)(r0 + r) * HID + c0 + x]);
  }
  __syncthreads();
#pragma unroll
  for (int i = 0; i < 16; ++i) {
    int cc = i * 4 + y;
    o[(size_t)(c0 + cc) * HID + r0 + x] = tile[x][cc];
  }
}

// ---------- kernel 3: bf16 GEMM  C[M,N] = A[M,K] @ (BT[N,K])^T ----------
// m97 structure. z==0 (emb_q) scaled by (1/8)*ln2inv (exp2 domain).
// z==2 (emb_v) written in PACKED V-FRAG layout (R9-verified).
__global__ __launch_bounds__(256) void k_gemm(const u16* __restrict__ Aall,
                                              const u16* __restrict__ BTall,
                                              u16* __restrict__ Call,
                                              u16* __restrict__ Vfrag) {
  const u16* A  = Aall  + (size_t)blockIdx.z * NELEM;
  const u16* BT = BTall + (size_t)blockIdx.z * WELEM;
  u16*       C  = Call  + (size_t)blockIdx.z * NELEM;
  int row0 = blockIdx.y * 128, col0 = blockIdx.x * 128;

  __shared__ __align__(16) u16 sA[128 * 32];
  __shared__ __align__(16) u16 sB[128 * 32];

  int t = threadIdx.x;
  int wave = t >> 6, lane = t & 63;
  int lrow = lane & 15, lhi = lane >> 4;
  int wr = wave >> 1, wc = wave & 1;

  f32x4 acc[4][4] = {};

  for (int kt = 0; kt < HID; kt += 32) {
#pragma unroll
    for (int r = 0; r < 2; ++r) {
      int idx = r * 256 + t;
      int srow = idx >> 2, scol = (idx & 3) << 3;
      int ldsoff = (r * 256 + wave * 64) * 8;   // wave-uniform LDS base
      gload_lds16(A  + (size_t)(row0 + srow) * HID + kt + scol, sA + ldsoff);
      gload_lds16(BT + (size_t)(col0 + srow) * HID + kt + scol, sB + ldsoff);
    }
    __syncthreads();
    s16x8 af[4], bfr[4];
#pragma unroll
    for (int m = 0; m < 4; ++m)
      af[m] = *(const s16x8*)&sA[(wr * 64 + m * 16 + lrow) * 32 + lhi * 8];
#pragma unroll
    for (int n = 0; n < 4; ++n)
      bfr[n] = *(const s16x8*)&sB[(wc * 64 + n * 16 + lrow) * 32 + lhi * 8];
#pragma unroll
    for (int m = 0; m < 4; ++m)
#pragma unroll
      for (int n = 0; n < 4; ++n)
        acc[m][n] = mfma16(af[m], bfr[n], acc[m][n]);
    __syncthreads();
  }
  mfma_fence();
  if (blockIdx.z == 2) {
    // packed V-frag epilogue (R9-verified)
#pragma unroll
    for (int m = 0; m < 4; ++m)
#pragma unroll
      for (int n = 0; n < 4; ++n) {
        int rr = row0 + wr * 64 + m * 16 + lhi * 4;       // t-row of j=0
        int cc = col0 + wc * 64 + n * 16 + lrow;          // hidden col
        int bb = rr >> 11, tt = rr & 2047;
        int hh = cc >> 6, chl = cc & 63;
        size_t off = ((size_t)(bb * NH + hh)) * ((size_t)CH * S_) +
                     (size_t)(((tt >> 4) * 4 + (chl >> 4)) * 256 +
                              ((tt >> 2) & 3) * 64 + (chl & 15) * 4);
        u32 w0 = (u32)f2bf(acc[m][n][0]) | ((u32)f2bf(acc[m][n][1]) << 16);
        u32 w1 = (u32)f2bf(acc[m][n][2]) | ((u32)f2bf(acc[m][n][3]) << 16);
        uint2 w; w.x = w0; w.y = w1;
        *(uint2*)&Vfrag[off] = w;
      }
  } else {
    // z==0: fold 1/sqrt(64) AND 1/ln(2) so k_attn uses exp2f directly
    float scl = (blockIdx.z == 0) ? 0.125f * 1.44269504f : 1.0f;
#pragma unroll
    for (int m = 0; m < 4; ++m)
#pragma unroll
      for (int n = 0; n < 4; ++n)
#pragma unroll
        for (int j = 0; j < 4; ++j) {
          int rr = row0 + wr * 64 + m * 16 + lhi * 4 + j;
          int cc = col0 + wc * 64 + n * 16 + lrow;
          C[(size_t)rr * HID + cc] = f2bf(acc[m][n][j] * scl);
        }
  }
}

// ---------- kernel 4: causal flash attention, KV-SPLIT partials ----------
// R11 structure (8 waves x 16 q-rows, KVBLK=64, swapped QK^T, in-register P,
// packed V-frags, fixed-max exp2 softmax, KV-split halves, 32 waves/CU).
// R13 VALU diet: (1) QK SrcC = persistent zero reg (D!=C mfma16z) -> no
// per-chain v_movs, no s_nops in QK; (2) single s_nop before PV (cvtpk->SrcA);
// (3) loop unrolled x2 with flattened LDS so every ds_read is base-VGPR +
// immediate offset (per-step address VALU ~= 0).
__global__ __launch_bounds__(512) void k_attn(const u16* __restrict__ eq,
                                              const u16* __restrict__ ek,
                                              const u16* __restrict__ vf,
                                              float* __restrict__ op0,
                                              float* __restrict__ op1,
                                              float* __restrict__ lp) {
  int bh = blockIdx.x;                 // b*NH + h
  int b = bh >> 4, h = bh & 15;
  int yy = blockIdx.y;                 // heavy-first: qt = 15 - (yy>>1)
  int qt = 15 - (yy >> 1);
  int half = yy & 1;
  int q0b = qt * 128;
  int wave = threadIdx.x >> 6, lane = threadIdx.x & 63;
  int lrow = lane & 15, lhi = lane >> 4;
  int q0w = q0b + wave * 16;

  // flattened LDS: [0,4096) K buf0 | [4096,8192) K buf1
  //                [8192,12288) V buf0 | [12288,16384) V buf1   (u16 units)
  __shared__ __align__(16) u16 sKV[16384];

  const u16* gK = ek + (size_t)(b * S_) * HID + h * CH;
  const u16* gV = vf + (size_t)bh * ((size_t)CH * S_);

  // Q fragments (emb_q pre-scaled); swapped-QK B-frag layout.
  s16x8 qf[2];
  {
    size_t qbase = (size_t)(b * S_ + q0w + lrow) * HID + h * CH;
    qf[0] = *(const s16x8*)(eq + qbase + lhi * 8);
    qf[1] = *(const s16x8*)(eq + qbase + 32 + lhi * 8);
  }

  f32x4 o[4] = {};                 // accumulated ONLY by MFMA inside the loop
  f32x4 zreg = {0.f, 0.f, 0.f, 0.f};   // persistent SrcC zero (never rewritten)
  float lsum = 0.0f;

  // staging lane mapping (XOR-swizzled K; chunk = 8 t-rows; wave stages chunk w)
  int lr8 = lane >> 3, slot = lane & 7;
  int co = ((slot ^ lr8) << 3);    // inverse-swizzled source column (elems)

  // loop-invariant lane read bases (u16 units)
  int kb_lane = lrow * 64 + ((lhi ^ (lrow & 7)) << 3);   // K frag base (1st half)
  int vb_lane = lhi * 64 + lrow * 4;                     // V frag base

  int nst = qt + 1;                // steps in this half
  int sbase = half * nst;          // global step offset
  int tb0 = sbase * 64;

  // prologue: stage first tile of this half into buf0
  gload_lds16(gK + (size_t)(tb0 + wave * 8 + lr8) * HID + co, &sKV[wave * 512]);
  gload_lds16(gV + (size_t)(tb0 >> 4) * 1024 + wave * 512 + lane * 8,
              &sKV[8192 + wave * 512]);

#define ATTN_STEP(ST, BUF)                                                     \
  {                                                                            \
    int tb = (sbase + (ST)) * 64;                                              \
    __syncthreads();                                                           \
    if ((ST) + 1 < nst) {                                                      \
      int tb2 = tb + 64;                                                       \
      gload_lds16(gK + (size_t)(tb2 + wave * 8 + lr8) * HID + co,              \
                  &sKV[(1 - (BUF)) * 4096 + wave * 512]);                      \
      gload_lds16(gV + (size_t)(tb2 >> 4) * 1024 + wave * 512 + lane * 8,      \
                  &sKV[8192 + (1 - (BUF)) * 4096 + wave * 512]);               \
    }                                                                          \
    if (tb <= q0w + 15) {                                                      \
      f32x4 p[4];                                                              \
      _Pragma("unroll")                                                        \
      for (int kvf = 0; kvf < 4; ++kvf) {                                      \
        s16x8 k0 = *(const s16x8*)&sKV[(BUF) * 4096 + kvf * 1024 + kb_lane];   \
        s16x8 k1 = *(const s16x8*)&sKV[(BUF) * 4096 + kvf * 1024 +             \
                                       (kb_lane ^ 32)];                        \
        p[kvf] = mfma16z(k0, qf[0], zreg);                                     \
        p[kvf] = mfma16t(k1, qf[1], p[kvf]);                                   \
      }                                                                        \
      mfma_fence();                                                            \
      bool need_mask = (tb + 63 > q0w);                                        \
      s16x4 pa[4];                                                             \
      _Pragma("unroll")                                                        \
      for (int kvf = 0; kvf < 4; ++kvf) {                                      \
        float e[4];                                                            \
        _Pragma("unroll")                                                      \
        for (int j = 0; j < 4; ++j) {                                          \
          float v = p[kvf][j];                                                 \
          if (need_mask && (tb + kvf * 16 + lhi * 4 + j > q0w + lrow))         \
            v = -3.0e38f;                                                      \
          e[j] = exp2f(v);                                                     \
        }                                                                      \
        lsum += (e[0] + e[1]) + (e[2] + e[3]);                                 \
        union { u32 u[2]; s16x4 v4; } pk;                                      \
        pk.u[0] = cvtpk(e[0], e[1]);                                           \
        pk.u[1] = cvtpk(e[2], e[3]);                                           \
        pa[kvf] = pk.v4;                                                       \
      }                                                                        \
      asm volatile("s_nop 1" :::);  /* cvtpk(VALU) -> pa as MFMA SrcA guard */ \
      _Pragma("unroll")                                                        \
      for (int n = 0; n < 4; ++n)                                              \
        _Pragma("unroll")                                                      \
        for (int kvf = 0; kvf < 4; ++kvf) {                                    \
          s16x4 vfr = *(const s16x4*)&sKV[8192 + (BUF) * 4096 +                \
                                          (kvf * 4 + n) * 256 + vb_lane];      \
          o[n] = mfma16k16t(pa[kvf], vfr, o[n]);                               \
        }                                                                      \
    }                                                                          \
  }

  for (int st2 = 0; st2 < nst; st2 += 2) {
    ATTN_STEP(st2, 0);
    if (st2 + 1 < nst) ATTN_STEP(st2 + 1, 1);
  }
#undef ATTN_STEP

  mfma_fence();

  // reduce lsum across the 4 hi-groups: every lane ends with total for q = lrow
  lsum += __shfl_xor(lsum, 16);
  lsum += __shfl_xor(lsum, 32);

  float* ob = half ? op1 : op0;
#pragma unroll
  for (int j = 0; j < 4; ++j) {
    int q = q0w + lhi * 4 + j;
    float* op = ob + (size_t)(b * S_ + q) * HID + h * CH + lrow;
#pragma unroll
    for (int n = 0; n < 4; ++n)
      op[n * 16] = o[n][j];              // unnormalized partial
  }
  if (lhi == 0) {                        // one lane set per q-row
    int q = q0w + lrow;
    lp[(((size_t)half * B_ + b) * S_ + q) * NH + h] = lsum;
  }
}

// ---------- kernel 5: combine partials + normalize ----------
__global__ __launch_bounds__(256) void k_combine(float* __restrict__ out,
                                                 const float* __restrict__ p1,
                                                 const float* __restrict__ lp) {
  size_t i = ((size_t)blockIdx.x * 256 + threadIdx.x) * 4;
  size_t row = i >> 10;                  // b*S + s
  int h = (int)((i & 1023) >> 6);
  size_t b = row >> 11, s = row & 2047;
  float l0 = lp[((0 * B_ + b) * S_ + s) * NH + h];
  float l1 = lp[((1 * B_ + b) * S_ + s) * NH + h];
  float inv = 1.0f / (l0 + l1);
  f32x4 a = *(const f32x4*)(out + i);
  f32x4 c = *(const f32x4*)(p1 + i);
#pragma unroll
  for (int k = 0; k < 4; ++k) a[k] = (a[k] + c[k]) * inv;
  *(f32x4*)(out + i) = a;
}

// ---------- launch ----------
extern "C" void kernel_launch(void* const* d_in, const int* in_sizes, int n_in,
                              void* d_out, int out_size, void* d_ws, size_t ws_size,
                              hipStream_t stream) {
  const float* q  = (const float*)d_in[0];
  const float* k  = (const float*)d_in[1];
  const float* v  = (const float*)d_in[2];
  const float* wq = (const float*)d_in[3];
  const float* wk = (const float*)d_in[4];
  const float* wv = (const float*)d_in[5];
  float* out = (float*)d_out;

  u16* qkv = (u16*)d_ws;                 // 3 * NELEM (dead after k_gemm)
  u16* wT  = qkv + 3 * NELEM;            // 3 * WELEM (dead after k_gemm)
  u16* emb = wT + 3 * WELEM;             // 3 * NELEM (z2 slot holds V-frag)
  u16* vfr = emb + 2 * NELEM;            // packed V-frag written by k_gemm z==2

  // partial buffers reuse dead regions: op0 = d_out, op1 + lp in qkv region
  float* op1 = (float*)d_ws;             // NELEM fp32 = 16 MB (< qkv's 24 MB)
  float* lp  = op1 + NELEM;              // 2*B*S*NH fp32 = 512 KB

  k_convert<<<dim3(2048, 3), 256, 0, stream>>>(q, k, v, qkv);
  k_transposeW<<<dim3(16, 16, 3), 256, 0, stream>>>(wq, wk, wv, wT);
  k_gemm<<<dim3(HID / 128, MTOT / 128, 3), 256, 0, stream>>>(qkv, wT, emb, vfr);
  k_attn<<<dim3(B_ * NH, 32), 512, 0, stream>>>(emb, emb + NELEM, vfr,
                                                out, op1, lp);
  k_combine<<<dim3(NELEM / (256 * 4)), 256, 0, stream>>>(out, op1, lp);
}

// Round 14
// 97.316 us; speedup vs baseline: 1.1503x; 1.0485x over previous
//
#include <hip/hip_runtime.h>
#include <stdint.h>

// Problem constants
#define B_   2
#define S_   2048
#define HID  1024
#define NH   16
#define CH   64
#define MTOT (B_ * S_)          // 4096 rows
#define NELEM ((size_t)MTOT * HID)   // 4,194,304 per matrix
#define WELEM ((size_t)HID * HID)    // 1,048,576 per weight

typedef unsigned short u16;
typedef unsigned int u32;
typedef __attribute__((ext_vector_type(4))) float f32x4;
typedef __attribute__((ext_vector_type(8))) short s16x8;
typedef __attribute__((ext_vector_type(4))) short s16x4;

// ---------- helpers ----------
__device__ __forceinline__ u16 f2bf(float f) {
  union { float f; unsigned u; } v; v.f = f;
  unsigned u = v.u;
  return (u16)((u + 0x7FFFu + ((u >> 16) & 1u)) >> 16);  // RNE (R3/R4-verified)
}

__device__ __forceinline__ f32x4 mfma16(s16x8 a, s16x8 b, f32x4 c) {
  // v_mfma_f32_16x16x32_bf16 (m89-verified layouts). GEMM-only (12 rounds clean).
  asm("v_mfma_f32_16x16x32_bf16 %0, %1, %2, %0" : "+v"(c) : "v"(a), "v"(b));
  return c;
}

// D != C form: SrcC is a separate (persistent, never-rewritten) register --
// no per-chain v_mov copies, hence NO VALU->SrcC hazard, no s_nop needed.
__device__ __forceinline__ f32x4 mfma16z(s16x8 a, s16x8 b, f32x4 c) {
  f32x4 d;
  asm("v_mfma_f32_16x16x32_bf16 %0, %1, %2, %3"
      : "=&v"(d) : "v"(a), "v"(b), "v"(c));
  return d;
}

// Tied same-register accumulate (HW-interlocked MFMA->MFMA same-acc chain).
__device__ __forceinline__ f32x4 mfma16t(s16x8 a, s16x8 b, f32x4 c) {
  asm("v_mfma_f32_16x16x32_bf16 %0, %1, %2, %0" : "+&v"(c) : "v"(a), "v"(b));
  return c;
}

// 16x16x16 bf16, tied accumulate (o[n] regs only ever written by MFMA in-loop).
__device__ __forceinline__ f32x4 mfma16k16t(s16x4 a, s16x4 b, f32x4 c) {
  asm("v_mfma_f32_16x16x16_bf16 %0, %1, %2, %0" : "+&v"(c) : "v"(a), "v"(b));
  return c;
}

__device__ __forceinline__ u32 cvtpk(float lo, float hi) {
  u32 r;
  asm("v_cvt_pk_bf16_f32 %0, %1, %2" : "=v"(r) : "v"(lo), "v"(hi));
  return r;
}

// 24-cycle fence before VALU reads of MFMA D results.
__device__ __forceinline__ void mfma_fence() {
  asm volatile("s_nop 7\n\ts_nop 7\n\ts_nop 7" ::: );
}

__device__ __forceinline__ void gload_lds16(const u16* g, u16* l) {
  __builtin_amdgcn_global_load_lds((const __attribute__((address_space(1))) void*)g,
                                   (__attribute__((address_space(3))) void*)l,
                                   16, 0, 0);
}

// ---------- kernel 1: fp32 -> bf16 convert of q,k,v ----------
__global__ __launch_bounds__(256) void k_convert(const float* __restrict__ a,
                                                 const float* __restrict__ b,
                                                 const float* __restrict__ c,
                                                 u16* __restrict__ out) {
  const float* src = (blockIdx.y == 0) ? a : (blockIdx.y == 1) ? b : c;
  u16* dst = out + (size_t)blockIdx.y * NELEM;
  size_t i = ((size_t)blockIdx.x * 256 + threadIdx.x) * 8;
  f32x4 v0 = *(const f32x4*)(src + i);
  f32x4 v1 = *(const f32x4*)(src + i + 4);
  s16x8 r;
#pragma unroll
  for (int k = 0; k < 4; ++k) { r[k] = (short)f2bf(v0[k]); r[4 + k] = (short)f2bf(v1[k]); }
  *(s16x8*)(dst + i) = r;
}

// ---------- kernel 2: W (fp32 [K][N]) -> W^T (bf16 [N][K]) ----------
__global__ __launch_bounds__(256) void k_transposeW(const float* __restrict__ w0,
                                                    const float* __restrict__ w1,
                                                    const float* __restrict__ w2,
                                                    u16* __restrict__ wT) {
  const float* w = (blockIdx.z == 0) ? w0 : (blockIdx.z == 1) ? w1 : w2;
  u16* o = wT + (size_t)blockIdx.z * WELEM;
  __shared__ u16 tile[64][65];
  int x = threadIdx.x & 63, y = threadIdx.x >> 6;
  int r0 = blockIdx.x * 64, c0 = blockIdx.y * 64;
#pragma unroll
  for (int i = 0; i < 16; ++i) {
    int r = i * 4 + y;
    tile[r][x] = f2bf(w[(size_t)(r0 + r) * HID + c0 + x]);
  }
  __syncthreads();
#pragma unroll
  for (int i = 0; i < 16; ++i) {
    int cc = i * 4 + y;
    o[(size_t)(c0 + cc) * HID + r0 + x] = tile[x][cc];
  }
}

// ---------- kernel 3: bf16 GEMM  C[M,N] = A[M,K] @ (BT[N,K])^T ----------
// m97 structure. z==0 (emb_q) scaled by (1/8)*ln2inv (exp2 domain).
// z==2 (emb_v) written in PACKED V-FRAG layout (R9-verified).
// R14: 1D grid + XCD-chunk swizzle. lin%8 = XCD (dispatch round-robin);
// each XCD gets 96 CONSECUTIVE chunk-ids = 12 complete A row-panels, so the
// 8 col-blocks sharing an A panel hit the SAME XCD's L2 (FETCH 101->~35MB).
__global__ __launch_bounds__(256) void k_gemm(const u16* __restrict__ Aall,
                                              const u16* __restrict__ BTall,
                                              u16* __restrict__ Call,
                                              u16* __restrict__ Vfrag) {
  int lin = blockIdx.x;                  // 0..767
  int xcd = lin & 7;
  int chunk = xcd * 96 + (lin >> 3);     // contiguous 96-chunk per XCD
  int zz = chunk >> 8;                   // chunk / 256
  int rem = chunk & 255;
  int ty = rem >> 3;                     // row-tile 0..31 (A panel)
  int tx = rem & 7;                      // col-tile 0..7

  const u16* A  = Aall  + (size_t)zz * NELEM;
  const u16* BT = BTall + (size_t)zz * WELEM;
  u16*       C  = Call  + (size_t)zz * NELEM;
  int row0 = ty * 128, col0 = tx * 128;

  __shared__ __align__(16) u16 sA[128 * 32];
  __shared__ __align__(16) u16 sB[128 * 32];

  int t = threadIdx.x;
  int wave = t >> 6, lane = t & 63;
  int lrow = lane & 15, lhi = lane >> 4;
  int wr = wave >> 1, wc = wave & 1;

  f32x4 acc[4][4] = {};

  for (int kt = 0; kt < HID; kt += 32) {
#pragma unroll
    for (int r = 0; r < 2; ++r) {
      int idx = r * 256 + t;
      int srow = idx >> 2, scol = (idx & 3) << 3;
      int ldsoff = (r * 256 + wave * 64) * 8;   // wave-uniform LDS base
      gload_lds16(A  + (size_t)(row0 + srow) * HID + kt + scol, sA + ldsoff);
      gload_lds16(BT + (size_t)(col0 + srow) * HID + kt + scol, sB + ldsoff);
    }
    __syncthreads();
    s16x8 af[4], bfr[4];
#pragma unroll
    for (int m = 0; m < 4; ++m)
      af[m] = *(const s16x8*)&sA[(wr * 64 + m * 16 + lrow) * 32 + lhi * 8];
#pragma unroll
    for (int n = 0; n < 4; ++n)
      bfr[n] = *(const s16x8*)&sB[(wc * 64 + n * 16 + lrow) * 32 + lhi * 8];
#pragma unroll
    for (int m = 0; m < 4; ++m)
#pragma unroll
      for (int n = 0; n < 4; ++n)
        acc[m][n] = mfma16(af[m], bfr[n], acc[m][n]);
    __syncthreads();
  }
  mfma_fence();
  if (zz == 2) {
    // packed V-frag epilogue (R9-verified)
#pragma unroll
    for (int m = 0; m < 4; ++m)
#pragma unroll
      for (int n = 0; n < 4; ++n) {
        int rr = row0 + wr * 64 + m * 16 + lhi * 4;       // t-row of j=0
        int cc = col0 + wc * 64 + n * 16 + lrow;          // hidden col
        int bb = rr >> 11, tt = rr & 2047;
        int hh = cc >> 6, chl = cc & 63;
        size_t off = ((size_t)(bb * NH + hh)) * ((size_t)CH * S_) +
                     (size_t)(((tt >> 4) * 4 + (chl >> 4)) * 256 +
                              ((tt >> 2) & 3) * 64 + (chl & 15) * 4);
        u32 w0 = (u32)f2bf(acc[m][n][0]) | ((u32)f2bf(acc[m][n][1]) << 16);
        u32 w1 = (u32)f2bf(acc[m][n][2]) | ((u32)f2bf(acc[m][n][3]) << 16);
        uint2 w; w.x = w0; w.y = w1;
        *(uint2*)&Vfrag[off] = w;
      }
  } else {
    // z==0: fold 1/sqrt(64) AND 1/ln(2) so k_attn uses exp2f directly
    float scl = (zz == 0) ? 0.125f * 1.44269504f : 1.0f;
#pragma unroll
    for (int m = 0; m < 4; ++m)
#pragma unroll
      for (int n = 0; n < 4; ++n)
#pragma unroll
        for (int j = 0; j < 4; ++j) {
          int rr = row0 + wr * 64 + m * 16 + lhi * 4 + j;
          int cc = col0 + wc * 64 + n * 16 + lrow;
          C[(size_t)rr * HID + cc] = f2bf(acc[m][n][j] * scl);
        }
  }
}

// ---------- kernel 4: causal flash attention, KV-SPLIT partials ----------
// R13-verified: 8 waves x 16 q-rows, KVBLK=64, swapped QK^T, in-register P,
// packed V-frags, fixed-max exp2 softmax, KV-split halves (32 waves/CU),
// zero-SrcC QK MFMAs, single s_nop before PV, x2 unroll + flattened LDS.
__global__ __launch_bounds__(512) void k_attn(const u16* __restrict__ eq,
                                              const u16* __restrict__ ek,
                                              const u16* __restrict__ vf,
                                              float* __restrict__ op0,
                                              float* __restrict__ op1,
                                              float* __restrict__ lp) {
  int bh = blockIdx.x;                 // b*NH + h
  int b = bh >> 4, h = bh & 15;
  int yy = blockIdx.y;                 // heavy-first: qt = 15 - (yy>>1)
  int qt = 15 - (yy >> 1);
  int half = yy & 1;
  int q0b = qt * 128;
  int wave = threadIdx.x >> 6, lane = threadIdx.x & 63;
  int lrow = lane & 15, lhi = lane >> 4;
  int q0w = q0b + wave * 16;

  // flattened LDS: [0,4096) K buf0 | [4096,8192) K buf1
  //                [8192,12288) V buf0 | [12288,16384) V buf1   (u16 units)
  __shared__ __align__(16) u16 sKV[16384];

  const u16* gK = ek + (size_t)(b * S_) * HID + h * CH;
  const u16* gV = vf + (size_t)bh * ((size_t)CH * S_);

  // Q fragments (emb_q pre-scaled); swapped-QK B-frag layout.
  s16x8 qf[2];
  {
    size_t qbase = (size_t)(b * S_ + q0w + lrow) * HID + h * CH;
    qf[0] = *(const s16x8*)(eq + qbase + lhi * 8);
    qf[1] = *(const s16x8*)(eq + qbase + 32 + lhi * 8);
  }

  f32x4 o[4] = {};                 // accumulated ONLY by MFMA inside the loop
  f32x4 zreg = {0.f, 0.f, 0.f, 0.f};   // persistent SrcC zero (never rewritten)
  float lsum = 0.0f;

  // staging lane mapping (XOR-swizzled K; chunk = 8 t-rows; wave stages chunk w)
  int lr8 = lane >> 3, slot = lane & 7;
  int co = ((slot ^ lr8) << 3);    // inverse-swizzled source column (elems)

  // loop-invariant lane read bases (u16 units)
  int kb_lane = lrow * 64 + ((lhi ^ (lrow & 7)) << 3);   // K frag base (1st half)
  int vb_lane = lhi * 64 + lrow * 4;                     // V frag base

  int nst = qt + 1;                // steps in this half
  int sbase = half * nst;          // global step offset
  int tb0 = sbase * 64;

  // prologue: stage first tile of this half into buf0
  gload_lds16(gK + (size_t)(tb0 + wave * 8 + lr8) * HID + co, &sKV[wave * 512]);
  gload_lds16(gV + (size_t)(tb0 >> 4) * 1024 + wave * 512 + lane * 8,
              &sKV[8192 + wave * 512]);

#define ATTN_STEP(ST, BUF)                                                     \
  {                                                                            \
    int tb = (sbase + (ST)) * 64;                                              \
    __syncthreads();                                                           \
    if ((ST) + 1 < nst) {                                                      \
      int tb2 = tb + 64;                                                       \
      gload_lds16(gK + (size_t)(tb2 + wave * 8 + lr8) * HID + co,              \
                  &sKV[(1 - (BUF)) * 4096 + wave * 512]);                      \
      gload_lds16(gV + (size_t)(tb2 >> 4) * 1024 + wave * 512 + lane * 8,      \
                  &sKV[8192 + (1 - (BUF)) * 4096 + wave * 512]);               \
    }                                                                          \
    if (tb <= q0w + 15) {                                                      \
      f32x4 p[4];                                                              \
      _Pragma("unroll")                                                        \
      for (int kvf = 0; kvf < 4; ++kvf) {                                      \
        s16x8 k0 = *(const s16x8*)&sKV[(BUF) * 4096 + kvf * 1024 + kb_lane];   \
        s16x8 k1 = *(const s16x8*)&sKV[(BUF) * 4096 + kvf * 1024 +             \
                                       (kb_lane ^ 32)];                        \
        p[kvf] = mfma16z(k0, qf[0], zreg);                                     \
        p[kvf] = mfma16t(k1, qf[1], p[kvf]);                                   \
      }                                                                        \
      mfma_fence();                                                            \
      bool need_mask = (tb + 63 > q0w);                                        \
      s16x4 pa[4];                                                             \
      _Pragma("unroll")                                                        \
      for (int kvf = 0; kvf < 4; ++kvf) {                                      \
        float e[4];                                                            \
        _Pragma("unroll")                                                      \
        for (int j = 0; j < 4; ++j) {                                          \
          float v = p[kvf][j];                                                 \
          if (need_mask && (tb + kvf * 16 + lhi * 4 + j > q0w + lrow))         \
            v = -3.0e38f;                                                      \
          e[j] = exp2f(v);                                                     \
        }                                                                      \
        lsum += (e[0] + e[1]) + (e[2] + e[3]);                                 \
        union { u32 u[2]; s16x4 v4; } pk;                                      \
        pk.u[0] = cvtpk(e[0], e[1]);                                           \
        pk.u[1] = cvtpk(e[2], e[3]);                                           \
        pa[kvf] = pk.v4;                                                       \
      }                                                                        \
      asm volatile("s_nop 1" :::);  /* cvtpk(VALU) -> pa as MFMA SrcA guard */ \
      _Pragma("unroll")                                                        \
      for (int n = 0; n < 4; ++n)                                              \
        _Pragma("unroll")                                                      \
        for (int kvf = 0; kvf < 4; ++kvf) {                                    \
          s16x4 vfr = *(const s16x4*)&sKV[8192 + (BUF) * 4096 +                \
                                          (kvf * 4 + n) * 256 + vb_lane];      \
          o[n] = mfma16k16t(pa[kvf], vfr, o[n]);                               \
        }                                                                      \
    }                                                                          \
  }

  for (int st2 = 0; st2 < nst; st2 += 2) {
    ATTN_STEP(st2, 0);
    if (st2 + 1 < nst) ATTN_STEP(st2 + 1, 1);
  }
#undef ATTN_STEP

  mfma_fence();

  // reduce lsum across the 4 hi-groups: every lane ends with total for q = lrow
  lsum += __shfl_xor(lsum, 16);
  lsum += __shfl_xor(lsum, 32);

  float* ob = half ? op1 : op0;
#pragma unroll
  for (int j = 0; j < 4; ++j) {
    int q = q0w + lhi * 4 + j;
    float* op = ob + (size_t)(b * S_ + q) * HID + h * CH + lrow;
#pragma unroll
    for (int n = 0; n < 4; ++n)
      op[n * 16] = o[n][j];              // unnormalized partial
  }
  if (lhi == 0) {                        // one lane set per q-row
    int q = q0w + lrow;
    lp[(((size_t)half * B_ + b) * S_ + q) * NH + h] = lsum;
  }
}

// ---------- kernel 5: combine partials + normalize ----------
__global__ __launch_bounds__(256) void k_combine(float* __restrict__ out,
                                                 const float* __restrict__ p1,
                                                 const float* __restrict__ lp) {
  size_t i = ((size_t)blockIdx.x * 256 + threadIdx.x) * 4;
  size_t row = i >> 10;                  // b*S + s
  int h = (int)((i & 1023) >> 6);
  size_t b = row >> 11, s = row & 2047;
  float l0 = lp[((0 * B_ + b) * S_ + s) * NH + h];
  float l1 = lp[((1 * B_ + b) * S_ + s) * NH + h];
  float inv = 1.0f / (l0 + l1);
  f32x4 a = *(const f32x4*)(out + i);
  f32x4 c = *(const f32x4*)(p1 + i);
#pragma unroll
  for (int k = 0; k < 4; ++k) a[k] = (a[k] + c[k]) * inv;
  *(f32x4*)(out + i) = a;
}

// ---------- launch ----------
extern "C" void kernel_launch(void* const* d_in, const int* in_sizes, int n_in,
                              void* d_out, int out_size, void* d_ws, size_t ws_size,
                              hipStream_t stream) {
  const float* q  = (const float*)d_in[0];
  const float* k  = (const float*)d_in[1];
  const float* v  = (const float*)d_in[2];
  const float* wq = (const float*)d_in[3];
  const float* wk = (const float*)d_in[4];
  const float* wv = (const float*)d_in[5];
  float* out = (float*)d_out;

  u16* qkv = (u16*)d_ws;                 // 3 * NELEM (dead after k_gemm)
  u16* wT  = qkv + 3 * NELEM;            // 3 * WELEM (dead after k_gemm)
  u16* emb = wT + 3 * WELEM;             // 3 * NELEM (z2 slot holds V-frag)
  u16* vfr = emb + 2 * NELEM;            // packed V-frag written by k_gemm z==2

  // partial buffers reuse dead regions: op0 = d_out, op1 + lp in qkv region
  float* op1 = (float*)d_ws;             // NELEM fp32 = 16 MB (< qkv's 24 MB)
  float* lp  = op1 + NELEM;              // 2*B*S*NH fp32 = 512 KB

  k_convert<<<dim3(2048, 3), 256, 0, stream>>>(q, k, v, qkv);
  k_transposeW<<<dim3(16, 16, 3), 256, 0, stream>>>(wq, wk, wv, wT);
  k_gemm<<<dim3(768), 256, 0, stream>>>(qkv, wT, emb, vfr);
  k_attn<<<dim3(B_ * NH, 32), 512, 0, stream>>>(emb, emb + NELEM, vfr,
                                                out, op1, lp);
  k_combine<<<dim3(NELEM / (256 * 4)), 256, 0, stream>>>(out, op1, lp);
}

// Round 15
// 89.016 us; speedup vs baseline: 1.2576x; 1.0932x over previous
//
#include <hip/hip_runtime.h>
#include <stdint.h>

// Problem constants
#define B_   2
#define S_   2048
#define HID  1024
#define NH   16
#define CH   64
#define MTOT (B_ * S_)          // 4096 rows
#define NELEM ((size_t)MTOT * HID)   // 4,194,304 per matrix
#define WELEM ((size_t)HID * HID)    // 1,048,576 per weight

typedef unsigned short u16;
typedef unsigned int u32;
typedef __attribute__((ext_vector_type(4))) float f32x4;
typedef __attribute__((ext_vector_type(8))) short s16x8;
typedef __attribute__((ext_vector_type(4))) short s16x4;

// ---------- helpers ----------
__device__ __forceinline__ u16 f2bf(float f) {
  union { float f; unsigned u; } v; v.f = f;
  unsigned u = v.u;
  return (u16)((u + 0x7FFFu + ((u >> 16) & 1u)) >> 16);  // RNE (R3/R4-verified)
}

__device__ __forceinline__ f32x4 mfma16(s16x8 a, s16x8 b, f32x4 c) {
  // v_mfma_f32_16x16x32_bf16 (m89-verified layouts). GEMM-only (13 rounds clean).
  asm("v_mfma_f32_16x16x32_bf16 %0, %1, %2, %0" : "+v"(c) : "v"(a), "v"(b));
  return c;
}

// D != C form: SrcC is a separate (persistent, never-rewritten) register --
// no per-chain v_mov copies, hence NO VALU->SrcC hazard, no s_nop needed.
__device__ __forceinline__ f32x4 mfma16z(s16x8 a, s16x8 b, f32x4 c) {
  f32x4 d;
  asm("v_mfma_f32_16x16x32_bf16 %0, %1, %2, %3"
      : "=&v"(d) : "v"(a), "v"(b), "v"(c));
  return d;
}

// Tied same-register accumulate (HW-interlocked MFMA->MFMA same-acc chain).
__device__ __forceinline__ f32x4 mfma16t(s16x8 a, s16x8 b, f32x4 c) {
  asm("v_mfma_f32_16x16x32_bf16 %0, %1, %2, %0" : "+&v"(c) : "v"(a), "v"(b));
  return c;
}

// 16x16x16 bf16, tied accumulate (o[n] regs only ever written by MFMA in-loop).
__device__ __forceinline__ f32x4 mfma16k16t(s16x4 a, s16x4 b, f32x4 c) {
  asm("v_mfma_f32_16x16x16_bf16 %0, %1, %2, %0" : "+&v"(c) : "v"(a), "v"(b));
  return c;
}

__device__ __forceinline__ u32 cvtpk(float lo, float hi) {
  u32 r;
  asm("v_cvt_pk_bf16_f32 %0, %1, %2" : "=v"(r) : "v"(lo), "v"(hi));
  return r;
}

// 24-cycle fence before VALU reads of MFMA D results.
__device__ __forceinline__ void mfma_fence() {
  asm volatile("s_nop 7\n\ts_nop 7\n\ts_nop 7" ::: );
}

__device__ __forceinline__ void gload_lds16(const u16* g, u16* l) {
  __builtin_amdgcn_global_load_lds((const __attribute__((address_space(1))) void*)g,
                                   (__attribute__((address_space(3))) void*)l,
                                   16, 0, 0);
}

// ---------- kernel 1: W (fp32 [K][N]) -> W^T (bf16 [N][K]) ----------
__global__ __launch_bounds__(256) void k_transposeW(const float* __restrict__ w0,
                                                    const float* __restrict__ w1,
                                                    const float* __restrict__ w2,
                                                    u16* __restrict__ wT) {
  const float* w = (blockIdx.z == 0) ? w0 : (blockIdx.z == 1) ? w1 : w2;
  u16* o = wT + (size_t)blockIdx.z * WELEM;
  __shared__ u16 tile[64][65];
  int x = threadIdx.x & 63, y = threadIdx.x >> 6;
  int r0 = blockIdx.x * 64, c0 = blockIdx.y * 64;
#pragma unroll
  for (int i = 0; i < 16; ++i) {
    int r = i * 4 + y;
    tile[r][x] = f2bf(w[(size_t)(r0 + r) * HID + c0 + x]);
  }
  __syncthreads();
#pragma unroll
  for (int i = 0; i < 16; ++i) {
    int cc = i * 4 + y;
    o[(size_t)(c0 + cc) * HID + r0 + x] = tile[x][cc];
  }
}

// ---------- kernel 2: FUSED bf16 GEMM, fp32 A with in-staging convert ----------
// C[M,N] = cvt_bf16(Afp32)[M,K] @ (BT[N,K])^T. m97 structure, but A-staging is
// reg-staged: 2x dwordx4 fp32 loads -> 4x v_cvt_pk_bf16_f32 -> ds_write_b128
// to the SAME linear LDS offset global_load_lds used (read path untouched).
// B keeps async global_load_lds. This deletes the k_convert pass (72MB glue).
// z==0 (emb_q) scaled by (1/8)*ln2inv (exp2 domain). z==2 -> packed V-frags.
// R14 XCD-chunk swizzle: each XCD gets 96 consecutive chunks = 12 A panels.
__global__ __launch_bounds__(256) void k_gemm(const float* __restrict__ qf32,
                                              const float* __restrict__ kf32,
                                              const float* __restrict__ vf32,
                                              const u16* __restrict__ BTall,
                                              u16* __restrict__ Call,
                                              u16* __restrict__ Vfrag) {
  int lin = blockIdx.x;                  // 0..767
  int xcd = lin & 7;
  int chunk = xcd * 96 + (lin >> 3);     // contiguous 96-chunk per XCD
  int zz = chunk >> 8;                   // chunk / 256
  int rem = chunk & 255;
  int ty = rem >> 3;                     // row-tile 0..31 (A panel)
  int tx = rem & 7;                      // col-tile 0..7

  const float* Af = (zz == 0) ? qf32 : (zz == 1) ? kf32 : vf32;
  const u16* BT = BTall + (size_t)zz * WELEM;
  u16*       C  = Call  + (size_t)zz * NELEM;
  int row0 = ty * 128, col0 = tx * 128;

  __shared__ __align__(16) u16 sA[128 * 32];
  __shared__ __align__(16) u16 sB[128 * 32];

  int t = threadIdx.x;
  int wave = t >> 6, lane = t & 63;
  int lrow = lane & 15, lhi = lane >> 4;
  int wr = wave >> 1, wc = wave & 1;

  f32x4 acc[4][4] = {};

  for (int kt = 0; kt < HID; kt += 32) {
#pragma unroll
    for (int r = 0; r < 2; ++r) {
      int idx = r * 256 + t;
      int srow = idx >> 2, scol = (idx & 3) << 3;
      // B: async bf16 global->LDS (wave-uniform base + lane*16B)
      int ldsoff = (r * 256 + wave * 64) * 8;
      gload_lds16(BT + (size_t)(col0 + srow) * HID + kt + scol, sB + ldsoff);
      // A: fp32 -> bf16 reg-staging to the SAME linear element offset idx*8
      const float* ap = Af + (size_t)(row0 + srow) * HID + kt + scol;
      f32x4 a0 = *(const f32x4*)ap;
      f32x4 a1 = *(const f32x4*)(ap + 4);
      union { u32 u[4]; s16x8 v; } aw;
      aw.u[0] = cvtpk(a0[0], a0[1]);
      aw.u[1] = cvtpk(a0[2], a0[3]);
      aw.u[2] = cvtpk(a1[0], a1[1]);
      aw.u[3] = cvtpk(a1[2], a1[3]);
      *(s16x8*)&sA[idx * 8] = aw.v;
    }
    __syncthreads();
    s16x8 af[4], bfr[4];
#pragma unroll
    for (int m = 0; m < 4; ++m)
      af[m] = *(const s16x8*)&sA[(wr * 64 + m * 16 + lrow) * 32 + lhi * 8];
#pragma unroll
    for (int n = 0; n < 4; ++n)
      bfr[n] = *(const s16x8*)&sB[(wc * 64 + n * 16 + lrow) * 32 + lhi * 8];
#pragma unroll
    for (int m = 0; m < 4; ++m)
#pragma unroll
      for (int n = 0; n < 4; ++n)
        acc[m][n] = mfma16(af[m], bfr[n], acc[m][n]);
    __syncthreads();
  }
  mfma_fence();
  if (zz == 2) {
    // packed V-frag epilogue (R9-verified)
#pragma unroll
    for (int m = 0; m < 4; ++m)
#pragma unroll
      for (int n = 0; n < 4; ++n) {
        int rr = row0 + wr * 64 + m * 16 + lhi * 4;       // t-row of j=0
        int cc = col0 + wc * 64 + n * 16 + lrow;          // hidden col
        int bb = rr >> 11, tt = rr & 2047;
        int hh = cc >> 6, chl = cc & 63;
        size_t off = ((size_t)(bb * NH + hh)) * ((size_t)CH * S_) +
                     (size_t)(((tt >> 4) * 4 + (chl >> 4)) * 256 +
                              ((tt >> 2) & 3) * 64 + (chl & 15) * 4);
        u32 w0 = (u32)f2bf(acc[m][n][0]) | ((u32)f2bf(acc[m][n][1]) << 16);
        u32 w1 = (u32)f2bf(acc[m][n][2]) | ((u32)f2bf(acc[m][n][3]) << 16);
        uint2 w; w.x = w0; w.y = w1;
        *(uint2*)&Vfrag[off] = w;
      }
  } else {
    // z==0: fold 1/sqrt(64) AND 1/ln(2) so k_attn uses exp2f directly
    float scl = (zz == 0) ? 0.125f * 1.44269504f : 1.0f;
#pragma unroll
    for (int m = 0; m < 4; ++m)
#pragma unroll
      for (int n = 0; n < 4; ++n)
#pragma unroll
        for (int j = 0; j < 4; ++j) {
          int rr = row0 + wr * 64 + m * 16 + lhi * 4 + j;
          int cc = col0 + wc * 64 + n * 16 + lrow;
          C[(size_t)rr * HID + cc] = f2bf(acc[m][n][j] * scl);
        }
  }
}

// ---------- kernel 3: causal flash attention, KV-SPLIT partials ----------
// R13-verified: 8 waves x 16 q-rows, KVBLK=64, swapped QK^T, in-register P,
// packed V-frags, fixed-max exp2 softmax, KV-split halves (32 waves/CU),
// zero-SrcC QK MFMAs, single s_nop before PV, x2 unroll + flattened LDS.
__global__ __launch_bounds__(512) void k_attn(const u16* __restrict__ eq,
                                              const u16* __restrict__ ek,
                                              const u16* __restrict__ vf,
                                              float* __restrict__ op0,
                                              float* __restrict__ op1,
                                              float* __restrict__ lp) {
  int bh = blockIdx.x;                 // b*NH + h
  int b = bh >> 4, h = bh & 15;
  int yy = blockIdx.y;                 // heavy-first: qt = 15 - (yy>>1)
  int qt = 15 - (yy >> 1);
  int half = yy & 1;
  int q0b = qt * 128;
  int wave = threadIdx.x >> 6, lane = threadIdx.x & 63;
  int lrow = lane & 15, lhi = lane >> 4;
  int q0w = q0b + wave * 16;

  // flattened LDS: [0,4096) K buf0 | [4096,8192) K buf1
  //                [8192,12288) V buf0 | [12288,16384) V buf1   (u16 units)
  __shared__ __align__(16) u16 sKV[16384];

  const u16* gK = ek + (size_t)(b * S_) * HID + h * CH;
  const u16* gV = vf + (size_t)bh * ((size_t)CH * S_);

  // Q fragments (emb_q pre-scaled); swapped-QK B-frag layout.
  s16x8 qf[2];
  {
    size_t qbase = (size_t)(b * S_ + q0w + lrow) * HID + h * CH;
    qf[0] = *(const s16x8*)(eq + qbase + lhi * 8);
    qf[1] = *(const s16x8*)(eq + qbase + 32 + lhi * 8);
  }

  f32x4 o[4] = {};                 // accumulated ONLY by MFMA inside the loop
  f32x4 zreg = {0.f, 0.f, 0.f, 0.f};   // persistent SrcC zero (never rewritten)
  float lsum = 0.0f;

  // staging lane mapping (XOR-swizzled K; chunk = 8 t-rows; wave stages chunk w)
  int lr8 = lane >> 3, slot = lane & 7;
  int co = ((slot ^ lr8) << 3);    // inverse-swizzled source column (elems)

  // loop-invariant lane read bases (u16 units)
  int kb_lane = lrow * 64 + ((lhi ^ (lrow & 7)) << 3);   // K frag base (1st half)
  int vb_lane = lhi * 64 + lrow * 4;                     // V frag base

  int nst = qt + 1;                // steps in this half
  int sbase = half * nst;          // global step offset
  int tb0 = sbase * 64;

  // prologue: stage first tile of this half into buf0
  gload_lds16(gK + (size_t)(tb0 + wave * 8 + lr8) * HID + co, &sKV[wave * 512]);
  gload_lds16(gV + (size_t)(tb0 >> 4) * 1024 + wave * 512 + lane * 8,
              &sKV[8192 + wave * 512]);

#define ATTN_STEP(ST, BUF)                                                     \
  {                                                                            \
    int tb = (sbase + (ST)) * 64;                                              \
    __syncthreads();                                                           \
    if ((ST) + 1 < nst) {                                                      \
      int tb2 = tb + 64;                                                       \
      gload_lds16(gK + (size_t)(tb2 + wave * 8 + lr8) * HID + co,              \
                  &sKV[(1 - (BUF)) * 4096 + wave * 512]);                      \
      gload_lds16(gV + (size_t)(tb2 >> 4) * 1024 + wave * 512 + lane * 8,      \
                  &sKV[8192 + (1 - (BUF)) * 4096 + wave * 512]);               \
    }                                                                          \
    if (tb <= q0w + 15) {                                                      \
      f32x4 p[4];                                                              \
      _Pragma("unroll")                                                        \
      for (int kvf = 0; kvf < 4; ++kvf) {                                      \
        s16x8 k0 = *(const s16x8*)&sKV[(BUF) * 4096 + kvf * 1024 + kb_lane];   \
        s16x8 k1 = *(const s16x8*)&sKV[(BUF) * 4096 + kvf * 1024 +             \
                                       (kb_lane ^ 32)];                        \
        p[kvf] = mfma16z(k0, qf[0], zreg);                                     \
        p[kvf] = mfma16t(k1, qf[1], p[kvf]);                                   \
      }                                                                        \
      mfma_fence();                                                            \
      bool need_mask = (tb + 63 > q0w);                                        \
      s16x4 pa[4];                                                             \
      _Pragma("unroll")                                                        \
      for (int kvf = 0; kvf < 4; ++kvf) {                                      \
        float e[4];                                                            \
        _Pragma("unroll")                                                      \
        for (int j = 0; j < 4; ++j) {                                          \
          float v = p[kvf][j];                                                 \
          if (need_mask && (tb + kvf * 16 + lhi * 4 + j > q0w + lrow))         \
            v = -3.0e38f;                                                      \
          e[j] = exp2f(v);                                                     \
        }                                                                      \
        lsum += (e[0] + e[1]) + (e[2] + e[3]);                                 \
        union { u32 u[2]; s16x4 v4; } pk;                                      \
        pk.u[0] = cvtpk(e[0], e[1]);                                           \
        pk.u[1] = cvtpk(e[2], e[3]);                                           \
        pa[kvf] = pk.v4;                                                       \
      }                                                                        \
      asm volatile("s_nop 1" :::);  /* cvtpk(VALU) -> pa as MFMA SrcA guard */ \
      _Pragma("unroll")                                                        \
      for (int n = 0; n < 4; ++n)                                              \
        _Pragma("unroll")                                                      \
        for (int kvf = 0; kvf < 4; ++kvf) {                                    \
          s16x4 vfr = *(const s16x4*)&sKV[8192 + (BUF) * 4096 +                \
                                          (kvf * 4 + n) * 256 + vb_lane];      \
          o[n] = mfma16k16t(pa[kvf], vfr, o[n]);                               \
        }                                                                      \
    }                                                                          \
  }

  for (int st2 = 0; st2 < nst; st2 += 2) {
    ATTN_STEP(st2, 0);
    if (st2 + 1 < nst) ATTN_STEP(st2 + 1, 1);
  }
#undef ATTN_STEP

  mfma_fence();

  // reduce lsum across the 4 hi-groups: every lane ends with total for q = lrow
  lsum += __shfl_xor(lsum, 16);
  lsum += __shfl_xor(lsum, 32);

  float* ob = half ? op1 : op0;
#pragma unroll
  for (int j = 0; j < 4; ++j) {
    int q = q0w + lhi * 4 + j;
    float* op = ob + (size_t)(b * S_ + q) * HID + h * CH + lrow;
#pragma unroll
    for (int n = 0; n < 4; ++n)
      op[n * 16] = o[n][j];              // unnormalized partial
  }
  if (lhi == 0) {                        // one lane set per q-row
    int q = q0w + lrow;
    lp[(((size_t)half * B_ + b) * S_ + q) * NH + h] = lsum;
  }
}

// ---------- kernel 4: combine partials + normalize ----------
__global__ __launch_bounds__(256) void k_combine(float* __restrict__ out,
                                                 const float* __restrict__ p1,
                                                 const float* __restrict__ lp) {
  size_t i = ((size_t)blockIdx.x * 256 + threadIdx.x) * 4;
  size_t row = i >> 10;                  // b*S + s
  int h = (int)((i & 1023) >> 6);
  size_t b = row >> 11, s = row & 2047;
  float l0 = lp[((0 * B_ + b) * S_ + s) * NH + h];
  float l1 = lp[((1 * B_ + b) * S_ + s) * NH + h];
  float inv = 1.0f / (l0 + l1);
  f32x4 a = *(const f32x4*)(out + i);
  f32x4 c = *(const f32x4*)(p1 + i);
#pragma unroll
  for (int k = 0; k < 4; ++k) a[k] = (a[k] + c[k]) * inv;
  *(f32x4*)(out + i) = a;
}

// ---------- launch ----------
extern "C" void kernel_launch(void* const* d_in, const int* in_sizes, int n_in,
                              void* d_out, int out_size, void* d_ws, size_t ws_size,
                              hipStream_t stream) {
  const float* q  = (const float*)d_in[0];
  const float* k  = (const float*)d_in[1];
  const float* v  = (const float*)d_in[2];
  const float* wq = (const float*)d_in[3];
  const float* wk = (const float*)d_in[4];
  const float* wv = (const float*)d_in[5];
  float* out = (float*)d_out;

  // layout (unchanged offsets; first 24MB region now free for partials):
  u16* qkv = (u16*)d_ws;                 // [legacy region, now scratch]
  u16* wT  = qkv + 3 * NELEM;            // 3 * WELEM
  u16* emb = wT + 3 * WELEM;             // 3 * NELEM (z2 slot holds V-frag)
  u16* vfr = emb + 2 * NELEM;            // packed V-frag written by k_gemm z==2

  // partial buffers in the scratch region: op0 = d_out, op1 + lp
  float* op1 = (float*)d_ws;             // NELEM fp32 = 16 MB (< 24 MB region)
  float* lp  = op1 + NELEM;              // 2*B*S*NH fp32 = 512 KB

  k_transposeW<<<dim3(16, 16, 3), 256, 0, stream>>>(wq, wk, wv, wT);
  k_gemm<<<dim3(768), 256, 0, stream>>>(q, k, v, wT, emb, vfr);
  k_attn<<<dim3(B_ * NH, 32), 512, 0, stream>>>(emb, emb + NELEM, vfr,
                                                out, op1, lp);
  k_combine<<<dim3(NELEM / (256 * 4)), 256, 0, stream>>>(out, op1, lp);
}

// Round 16
// 88.052 us; speedup vs baseline: 1.2713x; 1.0109x over previous
//
#include <hip/hip_runtime.h>
#include <stdint.h>

// Problem constants
#define B_   2
#define S_   2048
#define HID  1024
#define NH   16
#define CH   64
#define MTOT (B_ * S_)          // 4096 rows
#define NELEM ((size_t)MTOT * HID)   // 4,194,304 per matrix
#define WELEM ((size_t)HID * HID)    // 1,048,576 per weight

typedef unsigned short u16;
typedef unsigned int u32;
typedef __attribute__((ext_vector_type(4))) float f32x4;
typedef __attribute__((ext_vector_type(8))) short s16x8;
typedef __attribute__((ext_vector_type(4))) short s16x4;

// ---------- helpers ----------
__device__ __forceinline__ u16 f2bf(float f) {
  union { float f; unsigned u; } v; v.f = f;
  unsigned u = v.u;
  return (u16)((u + 0x7FFFu + ((u >> 16) & 1u)) >> 16);  // RNE (R3/R4-verified)
}

__device__ __forceinline__ f32x4 mfma16(s16x8 a, s16x8 b, f32x4 c) {
  // v_mfma_f32_16x16x32_bf16 (m89-verified layouts). GEMM-only (14 rounds clean).
  asm("v_mfma_f32_16x16x32_bf16 %0, %1, %2, %0" : "+v"(c) : "v"(a), "v"(b));
  return c;
}

// D != C form: SrcC is a separate (persistent, never-rewritten) register.
__device__ __forceinline__ f32x4 mfma16z(s16x8 a, s16x8 b, f32x4 c) {
  f32x4 d;
  asm("v_mfma_f32_16x16x32_bf16 %0, %1, %2, %3"
      : "=&v"(d) : "v"(a), "v"(b), "v"(c));
  return d;
}

// Tied same-register accumulate (HW-interlocked MFMA->MFMA same-acc chain).
__device__ __forceinline__ f32x4 mfma16t(s16x8 a, s16x8 b, f32x4 c) {
  asm("v_mfma_f32_16x16x32_bf16 %0, %1, %2, %0" : "+&v"(c) : "v"(a), "v"(b));
  return c;
}

// 16x16x16 bf16, tied accumulate (o[n] regs only ever written by MFMA in-loop).
__device__ __forceinline__ f32x4 mfma16k16t(s16x4 a, s16x4 b, f32x4 c) {
  asm("v_mfma_f32_16x16x16_bf16 %0, %1, %2, %0" : "+&v"(c) : "v"(a), "v"(b));
  return c;
}

__device__ __forceinline__ u32 cvtpk(float lo, float hi) {
  u32 r;
  asm("v_cvt_pk_bf16_f32 %0, %1, %2" : "=v"(r) : "v"(lo), "v"(hi));
  return r;
}

// 24-cycle fence before VALU reads of MFMA D results.
__device__ __forceinline__ void mfma_fence() {
  asm volatile("s_nop 7\n\ts_nop 7\n\ts_nop 7" ::: );
}

__device__ __forceinline__ void gload_lds16(const u16* g, u16* l) {
  __builtin_amdgcn_global_load_lds((const __attribute__((address_space(1))) void*)g,
                                   (__attribute__((address_space(3))) void*)l,
                                   16, 0, 0);
}

// ---------- kernel 1: W (fp32 [K][N]) -> W^T (bf16 [N][K]) ----------
__global__ __launch_bounds__(256) void k_transposeW(const float* __restrict__ w0,
                                                    const float* __restrict__ w1,
                                                    const float* __restrict__ w2,
                                                    u16* __restrict__ wT) {
  const float* w = (blockIdx.z == 0) ? w0 : (blockIdx.z == 1) ? w1 : w2;
  u16* o = wT + (size_t)blockIdx.z * WELEM;
  __shared__ u16 tile[64][65];
  int x = threadIdx.x & 63, y = threadIdx.x >> 6;
  int r0 = blockIdx.x * 64, c0 = blockIdx.y * 64;
#pragma unroll
  for (int i = 0; i < 16; ++i) {
    int r = i * 4 + y;
    tile[r][x] = f2bf(w[(size_t)(r0 + r) * HID + c0 + x]);
  }
  __syncthreads();
#pragma unroll
  for (int i = 0; i < 16; ++i) {
    int cc = i * 4 + y;
    o[(size_t)(c0 + cc) * HID + r0 + x] = tile[x][cc];
  }
}

// ---------- kernel 2: FUSED bf16 GEMM, double-buffered, swizzled LDS ----------
// C = cvt_bf16(Afp32) @ BT^T. R16: (1) 2x LDS buffers; per K-step: barrier ->
// ISSUE next B gload_lds + next A fp32 reg-loads -> 16 MFMA on current tile
// (hides HBM latency) -> cvt + ds_write next A. (2) 16B-slot XOR swizzle
// (slot ^= (row>>1)&3): ds_read_b128 spreads 16 lanes over all 8 bank-groups
// (2-way = free). A swizzles the ds_write dest; B pre-swizzles the GLOBAL
// source (gload_lds dest stays linear, m173 pattern).
__global__ __launch_bounds__(256) void k_gemm(const float* __restrict__ qf32,
                                              const float* __restrict__ kf32,
                                              const float* __restrict__ vf32,
                                              const u16* __restrict__ BTall,
                                              u16* __restrict__ Call,
                                              u16* __restrict__ Vfrag) {
  int lin = blockIdx.x;                  // 0..767
  int xcd = lin & 7;
  int chunk = xcd * 96 + (lin >> 3);     // contiguous 96-chunk per XCD (R14)
  int zz = chunk >> 8;
  int rem = chunk & 255;
  int ty = rem >> 3;                     // row-tile 0..31 (A panel)
  int tx = rem & 7;                      // col-tile 0..7

  const float* Af = (zz == 0) ? qf32 : (zz == 1) ? kf32 : vf32;
  const u16* BT = BTall + (size_t)zz * WELEM;
  u16*       C  = Call  + (size_t)zz * NELEM;
  int row0 = ty * 128, col0 = tx * 128;

  __shared__ __align__(16) u16 sA[2][128 * 32];
  __shared__ __align__(16) u16 sB[2][128 * 32];

  int t = threadIdx.x;
  int wave = t >> 6, lane = t & 63;
  int lrow = lane & 15, lhi = lane >> 4;
  int wr = wave >> 1, wc = wave & 1;

  // staging thread mapping: idx in [0,512), srow = idx>>2, 16B-slot = idx&3
  // B global source col pre-swizzled: slot ^ ((srow>>1)&3)
  // A ds_write dest slot swizzled the same way; A global load stays linear.
  f32x4 acc[4][4] = {};

  // read-side swizzle term (loop-invariant): slot = lhi ^ ((lrow>>1)&3)
  int kswz = (lhi ^ ((lrow >> 1) & 3)) << 3;   // elem offset within row

#define STAGE_B(KT, BUF)                                                       \
  _Pragma("unroll")                                                            \
  for (int r = 0; r < 2; ++r) {                                                \
    int idx = r * 256 + t;                                                     \
    int srow = idx >> 2;                                                       \
    int scol = (((idx & 3) ^ ((srow >> 1) & 3)) << 3);                         \
    int ldsoff = (r * 256 + wave * 64) * 8;                                    \
    gload_lds16(BT + (size_t)(col0 + srow) * HID + (KT) + scol,                \
                &sB[BUF][0] + ldsoff);                                         \
  }

#define LOAD_A(KT)                                                             \
  _Pragma("unroll")                                                            \
  for (int r = 0; r < 2; ++r) {                                                \
    int idx = r * 256 + t;                                                     \
    const float* ap = Af + (size_t)(row0 + (idx >> 2)) * HID + (KT) +          \
                      ((idx & 3) << 3);                                        \
    areg0[r] = *(const f32x4*)ap;                                              \
    areg1[r] = *(const f32x4*)(ap + 4);                                        \
  }

#define WRITE_A(BUF)                                                           \
  _Pragma("unroll")                                                            \
  for (int r = 0; r < 2; ++r) {                                                \
    int idx = r * 256 + t;                                                     \
    int srow = idx >> 2;                                                       \
    int slot = (idx & 3) ^ ((srow >> 1) & 3);                                  \
    union { u32 u[4]; s16x8 v; } aw;                                           \
    aw.u[0] = cvtpk(areg0[r][0], areg0[r][1]);                                 \
    aw.u[1] = cvtpk(areg0[r][2], areg0[r][3]);                                 \
    aw.u[2] = cvtpk(areg1[r][0], areg1[r][1]);                                 \
    aw.u[3] = cvtpk(areg1[r][2], areg1[r][3]);                                 \
    *(s16x8*)&sA[BUF][srow * 32 + slot * 8] = aw.v;                            \
  }

  f32x4 areg0[2], areg1[2];
  // prologue: stage kt=0 into buf0
  STAGE_B(0, 0);
  LOAD_A(0);
  WRITE_A(0);

  for (int kt = 0; kt < HID; kt += 32) {
    int cur = (kt >> 5) & 1;
    __syncthreads();                       // buf[cur] ready (vmcnt drained)
    bool more = (kt + 32) < HID;
    if (more) {
      STAGE_B(kt + 32, 1 - cur);           // async, stays in flight
      LOAD_A(kt + 32);                     // issue fp32 loads, no wait yet
    }
    s16x8 af[4], bfr[4];
#pragma unroll
    for (int m = 0; m < 4; ++m)
      af[m] = *(const s16x8*)&sA[cur][(wr * 64 + m * 16 + lrow) * 32 + kswz];
#pragma unroll
    for (int n = 0; n < 4; ++n)
      bfr[n] = *(const s16x8*)&sB[cur][(wc * 64 + n * 16 + lrow) * 32 + kswz];
#pragma unroll
    for (int m = 0; m < 4; ++m)
#pragma unroll
      for (int n = 0; n < 4; ++n)
        acc[m][n] = mfma16(af[m], bfr[n], acc[m][n]);
    if (more) {
      WRITE_A(1 - cur);                    // waits A loads (latency hidden)
    }
  }
#undef STAGE_B
#undef LOAD_A
#undef WRITE_A
  mfma_fence();
  if (zz == 2) {
    // packed V-frag epilogue (R9-verified)
#pragma unroll
    for (int m = 0; m < 4; ++m)
#pragma unroll
      for (int n = 0; n < 4; ++n) {
        int rr = row0 + wr * 64 + m * 16 + lhi * 4;       // t-row of j=0
        int cc = col0 + wc * 64 + n * 16 + lrow;          // hidden col
        int bb = rr >> 11, tt = rr & 2047;
        int hh = cc >> 6, chl = cc & 63;
        size_t off = ((size_t)(bb * NH + hh)) * ((size_t)CH * S_) +
                     (size_t)(((tt >> 4) * 4 + (chl >> 4)) * 256 +
                              ((tt >> 2) & 3) * 64 + (chl & 15) * 4);
        u32 w0 = (u32)f2bf(acc[m][n][0]) | ((u32)f2bf(acc[m][n][1]) << 16);
        u32 w1 = (u32)f2bf(acc[m][n][2]) | ((u32)f2bf(acc[m][n][3]) << 16);
        uint2 w; w.x = w0; w.y = w1;
        *(uint2*)&Vfrag[off] = w;
      }
  } else {
    // z==0: fold 1/sqrt(64) AND 1/ln(2) so k_attn uses exp2f directly
    float scl = (zz == 0) ? 0.125f * 1.44269504f : 1.0f;
#pragma unroll
    for (int m = 0; m < 4; ++m)
#pragma unroll
      for (int n = 0; n < 4; ++n)
#pragma unroll
        for (int j = 0; j < 4; ++j) {
          int rr = row0 + wr * 64 + m * 16 + lhi * 4 + j;
          int cc = col0 + wc * 64 + n * 16 + lrow;
          C[(size_t)rr * HID + cc] = f2bf(acc[m][n][j] * scl);
        }
  }
}

// ---------- kernel 3: causal flash attention, KV-SPLIT partials ----------
// R13-verified: 8 waves x 16 q-rows, KVBLK=64, swapped QK^T, in-register P,
// packed V-frags, fixed-max exp2 softmax, KV-split halves (32 waves/CU),
// zero-SrcC QK MFMAs, single s_nop before PV, x2 unroll + flattened LDS.
__global__ __launch_bounds__(512) void k_attn(const u16* __restrict__ eq,
                                              const u16* __restrict__ ek,
                                              const u16* __restrict__ vf,
                                              float* __restrict__ op0,
                                              float* __restrict__ op1,
                                              float* __restrict__ lp) {
  int bh = blockIdx.x;                 // b*NH + h
  int b = bh >> 4, h = bh & 15;
  int yy = blockIdx.y;                 // heavy-first: qt = 15 - (yy>>1)
  int qt = 15 - (yy >> 1);
  int half = yy & 1;
  int q0b = qt * 128;
  int wave = threadIdx.x >> 6, lane = threadIdx.x & 63;
  int lrow = lane & 15, lhi = lane >> 4;
  int q0w = q0b + wave * 16;

  // flattened LDS: [0,4096) K buf0 | [4096,8192) K buf1
  //                [8192,12288) V buf0 | [12288,16384) V buf1   (u16 units)
  __shared__ __align__(16) u16 sKV[16384];

  const u16* gK = ek + (size_t)(b * S_) * HID + h * CH;
  const u16* gV = vf + (size_t)bh * ((size_t)CH * S_);

  // Q fragments (emb_q pre-scaled); swapped-QK B-frag layout.
  s16x8 qf[2];
  {
    size_t qbase = (size_t)(b * S_ + q0w + lrow) * HID + h * CH;
    qf[0] = *(const s16x8*)(eq + qbase + lhi * 8);
    qf[1] = *(const s16x8*)(eq + qbase + 32 + lhi * 8);
  }

  f32x4 o[4] = {};                 // accumulated ONLY by MFMA inside the loop
  f32x4 zreg = {0.f, 0.f, 0.f, 0.f};   // persistent SrcC zero (never rewritten)
  float lsum = 0.0f;

  // staging lane mapping (XOR-swizzled K; chunk = 8 t-rows; wave stages chunk w)
  int lr8 = lane >> 3, slot = lane & 7;
  int co = ((slot ^ lr8) << 3);    // inverse-swizzled source column (elems)

  // loop-invariant lane read bases (u16 units)
  int kb_lane = lrow * 64 + ((lhi ^ (lrow & 7)) << 3);   // K frag base (1st half)
  int vb_lane = lhi * 64 + lrow * 4;                     // V frag base

  int nst = qt + 1;                // steps in this half
  int sbase = half * nst;          // global step offset
  int tb0 = sbase * 64;

  // prologue: stage first tile of this half into buf0
  gload_lds16(gK + (size_t)(tb0 + wave * 8 + lr8) * HID + co, &sKV[wave * 512]);
  gload_lds16(gV + (size_t)(tb0 >> 4) * 1024 + wave * 512 + lane * 8,
              &sKV[8192 + wave * 512]);

#define ATTN_STEP(ST, BUF)                                                     \
  {                                                                            \
    int tb = (sbase + (ST)) * 64;                                              \
    __syncthreads();                                                           \
    if ((ST) + 1 < nst) {                                                      \
      int tb2 = tb + 64;                                                       \
      gload_lds16(gK + (size_t)(tb2 + wave * 8 + lr8) * HID + co,              \
                  &sKV[(1 - (BUF)) * 4096 + wave * 512]);                      \
      gload_lds16(gV + (size_t)(tb2 >> 4) * 1024 + wave * 512 + lane * 8,      \
                  &sKV[8192 + (1 - (BUF)) * 4096 + wave * 512]);               \
    }                                                                          \
    if (tb <= q0w + 15) {                                                      \
      f32x4 p[4];                                                              \
      _Pragma("unroll")                                                        \
      for (int kvf = 0; kvf < 4; ++kvf) {                                      \
        s16x8 k0 = *(const s16x8*)&sKV[(BUF) * 4096 + kvf * 1024 + kb_lane];   \
        s16x8 k1 = *(const s16x8*)&sKV[(BUF) * 4096 + kvf * 1024 +             \
                                       (kb_lane ^ 32)];                        \
        p[kvf] = mfma16z(k0, qf[0], zreg);                                     \
        p[kvf] = mfma16t(k1, qf[1], p[kvf]);                                   \
      }                                                                        \
      mfma_fence();                                                            \
      bool need_mask = (tb + 63 > q0w);                                        \
      s16x4 pa[4];                                                             \
      _Pragma("unroll")                                                        \
      for (int kvf = 0; kvf < 4; ++kvf) {                                      \
        float e[4];                                                            \
        _Pragma("unroll")                                                      \
        for (int j = 0; j < 4; ++j) {                                          \
          float v = p[kvf][j];                                                 \
          if (need_mask && (tb + kvf * 16 + lhi * 4 + j > q0w + lrow))         \
            v = -3.0e38f;                                                      \
          e[j] = exp2f(v);                                                     \
        }                                                                      \
        lsum += (e[0] + e[1]) + (e[2] + e[3]);                                 \
        union { u32 u[2]; s16x4 v4; } pk;                                      \
        pk.u[0] = cvtpk(e[0], e[1]);                                           \
        pk.u[1] = cvtpk(e[2], e[3]);                                           \
        pa[kvf] = pk.v4;                                                       \
      }                                                                        \
      asm volatile("s_nop 1" :::);  /* cvtpk(VALU) -> pa as MFMA SrcA guard */ \
      _Pragma("unroll")                                                        \
      for (int n = 0; n < 4; ++n)                                              \
        _Pragma("unroll")                                                      \
        for (int kvf = 0; kvf < 4; ++kvf) {                                    \
          s16x4 vfr = *(const s16x4*)&sKV[8192 + (BUF) * 4096 +                \
                                          (kvf * 4 + n) * 256 + vb_lane];      \
          o[n] = mfma16k16t(pa[kvf], vfr, o[n]);                               \
        }                                                                      \
    }                                                                          \
  }

  for (int st2 = 0; st2 < nst; st2 += 2) {
    ATTN_STEP(st2, 0);
    if (st2 + 1 < nst) ATTN_STEP(st2 + 1, 1);
  }
#undef ATTN_STEP

  mfma_fence();

  // reduce lsum across the 4 hi-groups: every lane ends with total for q = lrow
  lsum += __shfl_xor(lsum, 16);
  lsum += __shfl_xor(lsum, 32);

  float* ob = half ? op1 : op0;
#pragma unroll
  for (int j = 0; j < 4; ++j) {
    int q = q0w + lhi * 4 + j;
    float* op = ob + (size_t)(b * S_ + q) * HID + h * CH + lrow;
#pragma unroll
    for (int n = 0; n < 4; ++n)
      op[n * 16] = o[n][j];              // unnormalized partial
  }
  if (lhi == 0) {                        // one lane set per q-row
    int q = q0w + lrow;
    lp[(((size_t)half * B_ + b) * S_ + q) * NH + h] = lsum;
  }
}

// ---------- kernel 4: combine partials + normalize ----------
__global__ __launch_bounds__(256) void k_combine(float* __restrict__ out,
                                                 const float* __restrict__ p1,
                                                 const float* __restrict__ lp) {
  size_t i = ((size_t)blockIdx.x * 256 + threadIdx.x) * 4;
  size_t row = i >> 10;                  // b*S + s
  int h = (int)((i & 1023) >> 6);
  size_t b = row >> 11, s = row & 2047;
  float l0 = lp[((0 * B_ + b) * S_ + s) * NH + h];
  float l1 = lp[((1 * B_ + b) * S_ + s) * NH + h];
  float inv = 1.0f / (l0 + l1);
  f32x4 a = *(const f32x4*)(out + i);
  f32x4 c = *(const f32x4*)(p1 + i);
#pragma unroll
  for (int k = 0; k < 4; ++k) a[k] = (a[k] + c[k]) * inv;
  *(f32x4*)(out + i) = a;
}

// ---------- launch ----------
extern "C" void kernel_launch(void* const* d_in, const int* in_sizes, int n_in,
                              void* d_out, int out_size, void* d_ws, size_t ws_size,
                              hipStream_t stream) {
  const float* q  = (const float*)d_in[0];
  const float* k  = (const float*)d_in[1];
  const float* v  = (const float*)d_in[2];
  const float* wq = (const float*)d_in[3];
  const float* wk = (const float*)d_in[4];
  const float* wv = (const float*)d_in[5];
  float* out = (float*)d_out;

  // layout (unchanged offsets; first 24MB region is scratch for partials):
  u16* qkv = (u16*)d_ws;                 // [scratch region]
  u16* wT  = qkv + 3 * NELEM;            // 3 * WELEM
  u16* emb = wT + 3 * WELEM;             // 3 * NELEM (z2 slot holds V-frag)
  u16* vfr = emb + 2 * NELEM;            // packed V-frag written by k_gemm z==2

  float* op1 = (float*)d_ws;             // NELEM fp32 = 16 MB (< 24 MB region)
  float* lp  = op1 + NELEM;              // 2*B*S*NH fp32 = 512 KB

  k_transposeW<<<dim3(16, 16, 3), 256, 0, stream>>>(wq, wk, wv, wT);
  k_gemm<<<dim3(768), 256, 0, stream>>>(q, k, v, wT, emb, vfr);
  k_attn<<<dim3(B_ * NH, 32), 512, 0, stream>>>(emb, emb + NELEM, vfr,
                                                out, op1, lp);
  k_combine<<<dim3(NELEM / (256 * 4)), 256, 0, stream>>>(out, op1, lp);
}

// Round 17
// 83.335 us; speedup vs baseline: 1.3433x; 1.0566x over previous
//
#include <hip/hip_runtime.h>
#include <stdint.h>

// Problem constants
#define B_   2
#define S_   2048
#define HID  1024
#define NH   16
#define CH   64
#define MTOT (B_ * S_)          // 4096 rows
#define NELEM ((size_t)MTOT * HID)   // 4,194,304 per matrix
#define WELEM ((size_t)HID * HID)    // 1,048,576 per weight

typedef unsigned short u16;
typedef unsigned int u32;
typedef __attribute__((ext_vector_type(4))) float f32x4;
typedef __attribute__((ext_vector_type(8))) short s16x8;
typedef __attribute__((ext_vector_type(4))) short s16x4;

// ---------- helpers ----------
__device__ __forceinline__ u16 f2bf(float f) {
  union { float f; unsigned u; } v; v.f = f;
  unsigned u = v.u;
  return (u16)((u + 0x7FFFu + ((u >> 16) & 1u)) >> 16);  // RNE (R3/R4-verified)
}

__device__ __forceinline__ float bf2f(u16 h) {
  union { unsigned u; float f; } v; v.u = ((u32)h) << 16; return v.f;
}

__device__ __forceinline__ f32x4 mfma16(s16x8 a, s16x8 b, f32x4 c) {
  // v_mfma_f32_16x16x32_bf16 (m89-verified layouts). GEMM-only (15 rounds clean).
  asm("v_mfma_f32_16x16x32_bf16 %0, %1, %2, %0" : "+v"(c) : "v"(a), "v"(b));
  return c;
}

// D != C form: SrcC is a separate (persistent, never-rewritten) register.
__device__ __forceinline__ f32x4 mfma16z(s16x8 a, s16x8 b, f32x4 c) {
  f32x4 d;
  asm("v_mfma_f32_16x16x32_bf16 %0, %1, %2, %3"
      : "=&v"(d) : "v"(a), "v"(b), "v"(c));
  return d;
}

// Tied same-register accumulate (HW-interlocked MFMA->MFMA same-acc chain).
__device__ __forceinline__ f32x4 mfma16t(s16x8 a, s16x8 b, f32x4 c) {
  asm("v_mfma_f32_16x16x32_bf16 %0, %1, %2, %0" : "+&v"(c) : "v"(a), "v"(b));
  return c;
}

// 16x16x16 bf16, tied accumulate (o[n] regs only ever written by MFMA in-loop).
__device__ __forceinline__ f32x4 mfma16k16t(s16x4 a, s16x4 b, f32x4 c) {
  asm("v_mfma_f32_16x16x16_bf16 %0, %1, %2, %0" : "+&v"(c) : "v"(a), "v"(b));
  return c;
}

__device__ __forceinline__ u32 cvtpk(float lo, float hi) {
  u32 r;
  asm("v_cvt_pk_bf16_f32 %0, %1, %2" : "=v"(r) : "v"(lo), "v"(hi));
  return r;
}

// 24-cycle fence before VALU reads of MFMA D results.
__device__ __forceinline__ void mfma_fence() {
  asm volatile("s_nop 7\n\ts_nop 7\n\ts_nop 7" ::: );
}

__device__ __forceinline__ void gload_lds16(const u16* g, u16* l) {
  __builtin_amdgcn_global_load_lds((const __attribute__((address_space(1))) void*)g,
                                   (__attribute__((address_space(3))) void*)l,
                                   16, 0, 0);
}

// ---------- kernel 1: W (fp32 [K][N]) -> W^T (bf16 [N][K]) ----------
__global__ __launch_bounds__(256) void k_transposeW(const float* __restrict__ w0,
                                                    const float* __restrict__ w1,
                                                    const float* __restrict__ w2,
                                                    u16* __restrict__ wT) {
  const float* w = (blockIdx.z == 0) ? w0 : (blockIdx.z == 1) ? w1 : w2;
  u16* o = wT + (size_t)blockIdx.z * WELEM;
  __shared__ u16 tile[64][65];
  int x = threadIdx.x & 63, y = threadIdx.x >> 6;
  int r0 = blockIdx.x * 64, c0 = blockIdx.y * 64;
#pragma unroll
  for (int i = 0; i < 16; ++i) {
    int r = i * 4 + y;
    tile[r][x] = f2bf(w[(size_t)(r0 + r) * HID + c0 + x]);
  }
  __syncthreads();
#pragma unroll
  for (int i = 0; i < 16; ++i) {
    int cc = i * 4 + y;
    o[(size_t)(c0 + cc) * HID + r0 + x] = tile[x][cc];
  }
}

// ---------- kernel 2: FUSED bf16 GEMM, double-buffered, swizzled LDS ----------
// (R16-verified: conflicts = 0.) C = cvt_bf16(Afp32) @ BT^T. 2x LDS buffers;
// per K-step: barrier -> issue next B gload_lds + next A fp32 loads -> 16 MFMA
// -> cvt + ds_write next A. 16B-slot XOR swizzle (slot ^= (row>>1)&3).
__global__ __launch_bounds__(256) void k_gemm(const float* __restrict__ qf32,
                                              const float* __restrict__ kf32,
                                              const float* __restrict__ vf32,
                                              const u16* __restrict__ BTall,
                                              u16* __restrict__ Call,
                                              u16* __restrict__ Vfrag) {
  int lin = blockIdx.x;                  // 0..767
  int xcd = lin & 7;
  int chunk = xcd * 96 + (lin >> 3);     // contiguous 96-chunk per XCD (R14)
  int zz = chunk >> 8;
  int rem = chunk & 255;
  int ty = rem >> 3;                     // row-tile 0..31 (A panel)
  int tx = rem & 7;                      // col-tile 0..7

  const float* Af = (zz == 0) ? qf32 : (zz == 1) ? kf32 : vf32;
  const u16* BT = BTall + (size_t)zz * WELEM;
  u16*       C  = Call  + (size_t)zz * NELEM;
  int row0 = ty * 128, col0 = tx * 128;

  __shared__ __align__(16) u16 sA[2][128 * 32];
  __shared__ __align__(16) u16 sB[2][128 * 32];

  int t = threadIdx.x;
  int wave = t >> 6, lane = t & 63;
  int lrow = lane & 15, lhi = lane >> 4;
  int wr = wave >> 1, wc = wave & 1;

  f32x4 acc[4][4] = {};
  int kswz = (lhi ^ ((lrow >> 1) & 3)) << 3;   // read-side swizzle (invariant)

#define STAGE_B(KT, BUF)                                                       \
  _Pragma("unroll")                                                            \
  for (int r = 0; r < 2; ++r) {                                                \
    int idx = r * 256 + t;                                                     \
    int srow = idx >> 2;                                                       \
    int scol = (((idx & 3) ^ ((srow >> 1) & 3)) << 3);                         \
    int ldsoff = (r * 256 + wave * 64) * 8;                                    \
    gload_lds16(BT + (size_t)(col0 + srow) * HID + (KT) + scol,                \
                &sB[BUF][0] + ldsoff);                                         \
  }

#define LOAD_A(KT)                                                             \
  _Pragma("unroll")                                                            \
  for (int r = 0; r < 2; ++r) {                                                \
    int idx = r * 256 + t;                                                     \
    const float* ap = Af + (size_t)(row0 + (idx >> 2)) * HID + (KT) +          \
                      ((idx & 3) << 3);                                        \
    areg0[r] = *(const f32x4*)ap;                                              \
    areg1[r] = *(const f32x4*)(ap + 4);                                        \
  }

#define WRITE_A(BUF)                                                           \
  _Pragma("unroll")                                                            \
  for (int r = 0; r < 2; ++r) {                                                \
    int idx = r * 256 + t;                                                     \
    int srow = idx >> 2;                                                       \
    int slot = (idx & 3) ^ ((srow >> 1) & 3);                                  \
    union { u32 u[4]; s16x8 v; } aw;                                           \
    aw.u[0] = cvtpk(areg0[r][0], areg0[r][1]);                                 \
    aw.u[1] = cvtpk(areg0[r][2], areg0[r][3]);                                 \
    aw.u[2] = cvtpk(areg1[r][0], areg1[r][1]);                                 \
    aw.u[3] = cvtpk(areg1[r][2], areg1[r][3]);                                 \
    *(s16x8*)&sA[BUF][srow * 32 + slot * 8] = aw.v;                            \
  }

  f32x4 areg0[2], areg1[2];
  STAGE_B(0, 0);
  LOAD_A(0);
  WRITE_A(0);

  for (int kt = 0; kt < HID; kt += 32) {
    int cur = (kt >> 5) & 1;
    __syncthreads();
    bool more = (kt + 32) < HID;
    if (more) {
      STAGE_B(kt + 32, 1 - cur);
      LOAD_A(kt + 32);
    }
    s16x8 af[4], bfr[4];
#pragma unroll
    for (int m = 0; m < 4; ++m)
      af[m] = *(const s16x8*)&sA[cur][(wr * 64 + m * 16 + lrow) * 32 + kswz];
#pragma unroll
    for (int n = 0; n < 4; ++n)
      bfr[n] = *(const s16x8*)&sB[cur][(wc * 64 + n * 16 + lrow) * 32 + kswz];
#pragma unroll
    for (int m = 0; m < 4; ++m)
#pragma unroll
      for (int n = 0; n < 4; ++n)
        acc[m][n] = mfma16(af[m], bfr[n], acc[m][n]);
    if (more) {
      WRITE_A(1 - cur);
    }
  }
#undef STAGE_B
#undef LOAD_A
#undef WRITE_A
  mfma_fence();
  if (zz == 2) {
    // packed V-frag epilogue (R9-verified)
#pragma unroll
    for (int m = 0; m < 4; ++m)
#pragma unroll
      for (int n = 0; n < 4; ++n) {
        int rr = row0 + wr * 64 + m * 16 + lhi * 4;       // t-row of j=0
        int cc = col0 + wc * 64 + n * 16 + lrow;          // hidden col
        int bb = rr >> 11, tt = rr & 2047;
        int hh = cc >> 6, chl = cc & 63;
        size_t off = ((size_t)(bb * NH + hh)) * ((size_t)CH * S_) +
                     (size_t)(((tt >> 4) * 4 + (chl >> 4)) * 256 +
                              ((tt >> 2) & 3) * 64 + (chl & 15) * 4);
        u32 w0 = (u32)f2bf(acc[m][n][0]) | ((u32)f2bf(acc[m][n][1]) << 16);
        u32 w1 = (u32)f2bf(acc[m][n][2]) | ((u32)f2bf(acc[m][n][3]) << 16);
        uint2 w; w.x = w0; w.y = w1;
        *(uint2*)&Vfrag[off] = w;
      }
  } else {
    // z==0: fold 1/sqrt(64) AND 1/ln(2) so k_attn uses exp2f directly
    float scl = (zz == 0) ? 0.125f * 1.44269504f : 1.0f;
#pragma unroll
    for (int m = 0; m < 4; ++m)
#pragma unroll
      for (int n = 0; n < 4; ++n)
#pragma unroll
        for (int j = 0; j < 4; ++j) {
          int rr = row0 + wr * 64 + m * 16 + lhi * 4 + j;
          int cc = col0 + wc * 64 + n * 16 + lrow;
          C[(size_t)rr * HID + cc] = f2bf(acc[m][n][j] * scl);
        }
  }
}

// ---------- kernel 3: causal flash attention, KV-SPLIT bf16 partials ----------
// R13-verified core. R17: (1) mask work hoisted into a WAVE-UNIFORM branch --
// interior steps (~85%) run a clean exp2-only path, only diagonal steps pay
// the 16 cmp + 16 cndmask; (2) partials written as bf16 (combine BW halves).
__global__ __launch_bounds__(512) void k_attn(const u16* __restrict__ eq,
                                              const u16* __restrict__ ek,
                                              const u16* __restrict__ vf,
                                              u16* __restrict__ op0,
                                              u16* __restrict__ op1,
                                              float* __restrict__ lp) {
  int bh = blockIdx.x;                 // b*NH + h
  int b = bh >> 4, h = bh & 15;
  int yy = blockIdx.y;                 // heavy-first: qt = 15 - (yy>>1)
  int qt = 15 - (yy >> 1);
  int half = yy & 1;
  int q0b = qt * 128;
  int wave = threadIdx.x >> 6, lane = threadIdx.x & 63;
  int lrow = lane & 15, lhi = lane >> 4;
  int q0w = q0b + wave * 16;

  // flattened LDS: [0,4096) K buf0 | [4096,8192) K buf1
  //                [8192,12288) V buf0 | [12288,16384) V buf1   (u16 units)
  __shared__ __align__(16) u16 sKV[16384];

  const u16* gK = ek + (size_t)(b * S_) * HID + h * CH;
  const u16* gV = vf + (size_t)bh * ((size_t)CH * S_);

  // Q fragments (emb_q pre-scaled); swapped-QK B-frag layout.
  s16x8 qf[2];
  {
    size_t qbase = (size_t)(b * S_ + q0w + lrow) * HID + h * CH;
    qf[0] = *(const s16x8*)(eq + qbase + lhi * 8);
    qf[1] = *(const s16x8*)(eq + qbase + 32 + lhi * 8);
  }

  f32x4 o[4] = {};                 // accumulated ONLY by MFMA inside the loop
  f32x4 zreg = {0.f, 0.f, 0.f, 0.f};   // persistent SrcC zero (never rewritten)
  float lsum = 0.0f;

  // staging lane mapping (XOR-swizzled K; chunk = 8 t-rows; wave stages chunk w)
  int lr8 = lane >> 3, slot = lane & 7;
  int co = ((slot ^ lr8) << 3);    // inverse-swizzled source column (elems)

  // loop-invariant lane read bases (u16 units)
  int kb_lane = lrow * 64 + ((lhi ^ (lrow & 7)) << 3);   // K frag base (1st half)
  int vb_lane = lhi * 64 + lrow * 4;                     // V frag base

  int nst = qt + 1;                // steps in this half
  int sbase = half * nst;          // global step offset
  int tb0 = sbase * 64;

  // prologue: stage first tile of this half into buf0
  gload_lds16(gK + (size_t)(tb0 + wave * 8 + lr8) * HID + co, &sKV[wave * 512]);
  gload_lds16(gV + (size_t)(tb0 >> 4) * 1024 + wave * 512 + lane * 8,
              &sKV[8192 + wave * 512]);

#define ATTN_STEP(ST, BUF)                                                     \
  {                                                                            \
    int tb = (sbase + (ST)) * 64;                                              \
    __syncthreads();                                                           \
    if ((ST) + 1 < nst) {                                                      \
      int tb2 = tb + 64;                                                       \
      gload_lds16(gK + (size_t)(tb2 + wave * 8 + lr8) * HID + co,              \
                  &sKV[(1 - (BUF)) * 4096 + wave * 512]);                      \
      gload_lds16(gV + (size_t)(tb2 >> 4) * 1024 + wave * 512 + lane * 8,      \
                  &sKV[8192 + (1 - (BUF)) * 4096 + wave * 512]);               \
    }                                                                          \
    if (tb <= q0w + 15) {                                                      \
      f32x4 p[4];                                                              \
      _Pragma("unroll")                                                        \
      for (int kvf = 0; kvf < 4; ++kvf) {                                      \
        s16x8 k0 = *(const s16x8*)&sKV[(BUF) * 4096 + kvf * 1024 + kb_lane];   \
        s16x8 k1 = *(const s16x8*)&sKV[(BUF) * 4096 + kvf * 1024 +             \
                                       (kb_lane ^ 32)];                        \
        p[kvf] = mfma16z(k0, qf[0], zreg);                                     \
        p[kvf] = mfma16t(k1, qf[1], p[kvf]);                                   \
      }                                                                        \
      mfma_fence();                                                            \
      s16x4 pa[4];                                                             \
      if (tb + 63 > q0w) {            /* diagonal step: wave-uniform branch */ \
        _Pragma("unroll")                                                      \
        for (int kvf = 0; kvf < 4; ++kvf) {                                    \
          float e[4];                                                          \
          _Pragma("unroll")                                                    \
          for (int j = 0; j < 4; ++j) {                                        \
            float v = p[kvf][j];                                               \
            if (tb + kvf * 16 + lhi * 4 + j > q0w + lrow) v = -3.0e38f;        \
            e[j] = exp2f(v);                                                   \
          }                                                                    \
          lsum += (e[0] + e[1]) + (e[2] + e[3]);                               \
          union { u32 u[2]; s16x4 v4; } pk;                                    \
          pk.u[0] = cvtpk(e[0], e[1]);                                         \
          pk.u[1] = cvtpk(e[2], e[3]);                                         \
          pa[kvf] = pk.v4;                                                     \
        }                                                                      \
      } else {                        /* interior step: no mask VALU at all */ \
        _Pragma("unroll")                                                      \
        for (int kvf = 0; kvf < 4; ++kvf) {                                    \
          float e[4];                                                          \
          _Pragma("unroll")                                                    \
          for (int j = 0; j < 4; ++j) e[j] = exp2f(p[kvf][j]);                 \
          lsum += (e[0] + e[1]) + (e[2] + e[3]);                               \
          union { u32 u[2]; s16x4 v4; } pk;                                    \
          pk.u[0] = cvtpk(e[0], e[1]);                                         \
          pk.u[1] = cvtpk(e[2], e[3]);                                         \
          pa[kvf] = pk.v4;                                                     \
        }                                                                      \
      }                                                                        \
      asm volatile("s_nop 1" :::);  /* cvtpk(VALU) -> pa as MFMA SrcA guard */ \
      _Pragma("unroll")                                                        \
      for (int n = 0; n < 4; ++n)                                              \
        _Pragma("unroll")                                                      \
        for (int kvf = 0; kvf < 4; ++kvf) {                                    \
          s16x4 vfr = *(const s16x4*)&sKV[8192 + (BUF) * 4096 +                \
                                          (kvf * 4 + n) * 256 + vb_lane];      \
          o[n] = mfma16k16t(pa[kvf], vfr, o[n]);                               \
        }                                                                      \
    }                                                                          \
  }

  for (int st2 = 0; st2 < nst; st2 += 2) {
    ATTN_STEP(st2, 0);
    if (st2 + 1 < nst) ATTN_STEP(st2 + 1, 1);
  }
#undef ATTN_STEP

  mfma_fence();

  // reduce lsum across the 4 hi-groups: every lane ends with total for q = lrow
  lsum += __shfl_xor(lsum, 16);
  lsum += __shfl_xor(lsum, 32);

  u16* ob = half ? op1 : op0;
#pragma unroll
  for (int j = 0; j < 4; ++j) {
    int q = q0w + lhi * 4 + j;
    u16* op = ob + (size_t)(b * S_ + q) * HID + h * CH + lrow;
#pragma unroll
    for (int n = 0; n < 4; ++n)
      op[n * 16] = f2bf(o[n][j]);        // unnormalized bf16 partial
  }
  if (lhi == 0) {                        // one lane set per q-row
    int q = q0w + lrow;
    lp[(((size_t)half * B_ + b) * S_ + q) * NH + h] = lsum;
  }
}

// ---------- kernel 4: combine bf16 partials + normalize -> fp32 out ----------
__global__ __launch_bounds__(256) void k_combine(float* __restrict__ out,
                                                 const u16* __restrict__ p0,
                                                 const u16* __restrict__ p1,
                                                 const float* __restrict__ lp) {
  size_t i = ((size_t)blockIdx.x * 256 + threadIdx.x) * 4;
  size_t row = i >> 10;                  // b*S + s
  int h = (int)((i & 1023) >> 6);
  size_t b = row >> 11, s = row & 2047;
  float l0 = lp[((0 * B_ + b) * S_ + s) * NH + h];
  float l1 = lp[((1 * B_ + b) * S_ + s) * NH + h];
  float inv = 1.0f / (l0 + l1);
  uint2 a = *(const uint2*)&p0[i];
  uint2 c = *(const uint2*)&p1[i];
  f32x4 r;
  r[0] = (bf2f((u16)(a.x & 0xFFFF)) + bf2f((u16)(c.x & 0xFFFF))) * inv;
  r[1] = (bf2f((u16)(a.x >> 16))    + bf2f((u16)(c.x >> 16)))    * inv;
  r[2] = (bf2f((u16)(a.y & 0xFFFF)) + bf2f((u16)(c.y & 0xFFFF))) * inv;
  r[3] = (bf2f((u16)(a.y >> 16))    + bf2f((u16)(c.y >> 16)))    * inv;
  *(f32x4*)(out + i) = r;
}

// ---------- launch ----------
extern "C" void kernel_launch(void* const* d_in, const int* in_sizes, int n_in,
                              void* d_out, int out_size, void* d_ws, size_t ws_size,
                              hipStream_t stream) {
  const float* q  = (const float*)d_in[0];
  const float* k  = (const float*)d_in[1];
  const float* v  = (const float*)d_in[2];
  const float* wq = (const float*)d_in[3];
  const float* wk = (const float*)d_in[4];
  const float* wv = (const float*)d_in[5];
  float* out = (float*)d_out;

  // layout: first 24MB region is scratch for partials; rest unchanged.
  u16* scratch = (u16*)d_ws;             // 3*NELEM u16 region
  u16* wT  = scratch + 3 * NELEM;        // 3 * WELEM
  u16* emb = wT + 3 * WELEM;             // 3 * NELEM (z2 slot holds V-frag)
  u16* vfr = emb + 2 * NELEM;            // packed V-frag written by k_gemm z==2

  u16* p0b = scratch;                    // NELEM bf16 = 8 MB
  u16* p1b = scratch + NELEM;            // NELEM bf16 = 8 MB
  float* lp = (float*)(scratch + 2 * NELEM);  // 2*B*S*NH fp32 = 512 KB

  k_transposeW<<<dim3(16, 16, 3), 256, 0, stream>>>(wq, wk, wv, wT);
  k_gemm<<<dim3(768), 256, 0, stream>>>(q, k, v, wT, emb, vfr);
  k_attn<<<dim3(B_ * NH, 32), 512, 0, stream>>>(emb, emb + NELEM, vfr,
                                                p0b, p1b, lp);
  k_combine<<<dim3(NELEM / (256 * 4)), 256, 0, stream>>>(out, p0b, p1b, lp);
}